// Round 3
// baseline (492.504 us; speedup 1.0000x reference)
//
#include <hip/hip_runtime.h>
#include <hip/hip_bf16.h>
#include <hip/hip_fp16.h>

#define NPOINTS 2048
#define BATCH   2
#define DIM     256
#define D2      128
#define D4      64
#define NHEAD   8
#define HDIM    32
#define KNNK    64
#define NROWS   (BATCH*NPOINTS)
#define SCALE_F 0.17677669529663687f

typedef unsigned short u16;
typedef _Float16 f16x8 __attribute__((ext_vector_type(8)));
typedef float f32x4 __attribute__((ext_vector_type(4)));

__device__ __forceinline__ u16 f2h(float f) {
  __half h = __float2half(f); u16 r; __builtin_memcpy(&r, &h, 2); return r;
}
__device__ __forceinline__ unsigned pkh2(float a, float b) {
  __half2 h = __floats2half2_rn(a, b); unsigned r; __builtin_memcpy(&r, &h, 4); return r;
}
__device__ __forceinline__ float2 uph2(unsigned u) {
  __half2 h; __builtin_memcpy(&h, &u, 4); return __half22float2(h);
}

#if __has_builtin(__builtin_amdgcn_fdot2)
typedef _Float16 hv2_t __attribute__((ext_vector_type(2)));
__device__ __forceinline__ float fdot2f(unsigned a, unsigned b, float c) {
  hv2_t x, y; __builtin_memcpy(&x, &a, 4); __builtin_memcpy(&y, &b, 4);
  return __builtin_amdgcn_fdot2(x, y, c, false);
}
#else
__device__ __forceinline__ float fdot2f(unsigned a, unsigned b, float c) {
  float2 x = uph2(a), y = uph2(b);
  return fmaf(x.x, y.x, fmaf(x.y, y.y, c));
}
#endif

// ---------------------------------------------------------------------------
// Kernel 1: exact KNN (64 smallest of 2048) per point. Distances stored f16.
// ---------------------------------------------------------------------------
__global__ __launch_bounds__(256) void knn_kernel(
    const float* __restrict__ xyz,
    int*    __restrict__ knn_idx,
    __half* __restrict__ knn_dist)
{
  __shared__ float dist[NPOINTS];
  __shared__ unsigned hist[256];
  __shared__ unsigned sh_sel, sh_below;

  const int bp = blockIdx.x;
  const int b  = bp >> 11;
  const int n  = bp & (NPOINTS - 1);
  const int t  = threadIdx.x;
  const float* P = xyz + (size_t)b * NPOINTS * 3;

  const float qx = P[n*3+0], qy = P[n*3+1], qz = P[n*3+2];
  const float r2n = qx*qx + qy*qy + qz*qz;
  for (int m = t; m < NPOINTS; m += 256) {
    float x = P[m*3+0], y = P[m*3+1], z = P[m*3+2];
    float r2m = x*x + y*y + z*z;
    float dt  = x*qx + y*qy + z*qz;
    float sq  = r2n + r2m - 2.f*dt;
    sq = fmaxf(sq, 0.f);
    dist[m] = (sq > 0.f) ? sqrtf(sq) : 0.f;
  }
  __syncthreads();

  unsigned prefix = 0u;
  int k_need = KNNK;
  for (int pass = 0; pass < 4; ++pass) {
    const int shift = 24 - pass*8;
    hist[t] = 0u;
    __syncthreads();
    for (int m = t; m < NPOINTS; m += 256) {
      unsigned bits = __float_as_uint(dist[m]);
      if (((bits >> shift) >> 8) == prefix)
        atomicAdd(&hist[(bits >> shift) & 255u], 1u);
    }
    __syncthreads();
    if (t < 64) {
      unsigned s0 = hist[t*4+0], s1 = hist[t*4+1], s2 = hist[t*4+2], s3 = hist[t*4+3];
      unsigned lsum = s0 + s1 + s2 + s3;
      unsigned scan = lsum;
      #pragma unroll
      for (int off = 1; off < 64; off <<= 1) {
        unsigned o = __shfl_up(scan, off);
        if (t >= off) scan += o;
      }
      unsigned excl = scan - lsum;
      unsigned kk = (unsigned)k_need;
      if (excl < kk && kk <= excl + lsum) {
        unsigned below = excl; int bin = t*4;
        if (kk > below + s0) { below += s0; bin++;
          if (kk > below + s1) { below += s1; bin++;
            if (kk > below + s2) { below += s2; bin++; } } }
        sh_sel = (unsigned)bin; sh_below = below;
      }
    }
    __syncthreads();
    prefix = (prefix << 8) | sh_sel;
    k_need -= (int)sh_below;
    __syncthreads();
  }
  const unsigned Tbits = prefix;
  const int base = KNNK - k_need;

  if (t < 64) {
    int*    oi = knn_idx  + (size_t)bp * KNNK;
    __half* od = knn_dist + (size_t)bp * KNNK;
    int taken = 0;
    for (int c = 0; c < NPOINTS/64; ++c) {
      int m = c*64 + t;
      float dv = dist[m];
      bool lt = (__float_as_uint(dv) < Tbits);
      unsigned long long msk = __ballot(lt);
      int off = __popcll(msk & ((1ull << t) - 1ull));
      if (lt) { oi[taken+off] = m; od[taken+off] = __float2half(dv); }
      taken += __popcll(msk);
    }
    int eq = 0;
    for (int c = 0; c < NPOINTS/64 && eq < k_need; ++c) {
      int m = c*64 + t;
      float dv = dist[m];
      bool e = (__float_as_uint(dv) == Tbits);
      unsigned long long msk = __ballot(e);
      int off = __popcll(msk & ((1ull << t) - 1ull));
      if (e && (eq + off) < k_need) { oi[base+eq+off] = m; od[base+eq+off] = __float2half(dv); }
      eq += __popcll(msk);
    }
  }
}

// ---------------------------------------------------------------------------
// Kernel 2: weight prep — f16-packed copies into ws.
//   wkT2   [d2][c][2]  pairs over d          (P2 g-fold)
//   w3Tf   [j][c]      identity copy         (P3 w3g-fold)
//   w3f2   [j2][c][2]  pairs over j          (P8b part2)
//   wvB2   [c2][d][2]  pairs over c          (P9)
//   w2frag MFMA B-fragments of de_w2:        (h2 MFMA)
//     idx ((n*2+ks)*64+l)*8+e = w2[i = ks*32+(l>>4)*8+e][j = n*16+(l&15)]
// ---------------------------------------------------------------------------
__global__ __launch_bounds__(256) void prep_kernel(
    const float* __restrict__ wk, const float* __restrict__ de_w3,
    const float* __restrict__ wv, const float* __restrict__ de_w2,
    u16* __restrict__ wkT2, u16* __restrict__ w3Tf, u16* __restrict__ w3f2,
    u16* __restrict__ wvB2, u16* __restrict__ w2frag)
{
  int tid = blockIdx.x*256 + threadIdx.x;
  if (tid < 65536) {
    int d = tid >> 8, c = tid & 255;
    wkT2[(d>>1)*512 + c*2 + (d&1)] = f2h(wk[c*DIM + d]);
  } else if (tid < 98304) {
    int o = tid - 65536;
    w3Tf[o] = f2h(de_w3[o]);                       // de_w3 is [128][256] row-major
  } else if (tid < 131072) {
    int o = tid - 98304; int j = o >> 8, c = o & 255;
    w3f2[(j>>1)*512 + c*2 + (j&1)] = f2h(de_w3[j*DIM + c]);
  } else if (tid < 196608) {
    int o = tid - 131072; int c = o >> 8, d = o & 255;
    wvB2[(c>>1)*512 + d*2 + (c&1)] = f2h(wv[c*DIM + d]);
  } else if (tid < 204800) {
    int o = tid - 196608;            // 0..8191
    int e = o & 7, l = (o >> 3) & 63, ks = (o >> 9) & 1, n = o >> 10;
    int i = ks*32 + ((l >> 4) << 3) + e;
    int j = n*16 + (l & 15);
    w2frag[o] = f2h(de_w2[i*D2 + j]);
  }
}

// ---------------------------------------------------------------------------
// Kernel 3: batched q projection, 16 rows/block. q -> d_out (scratch).
// ---------------------------------------------------------------------------
__global__ __launch_bounds__(256) void qproj_kernel(
    const float* __restrict__ features, const float* __restrict__ wq,
    const float* __restrict__ bq, float* __restrict__ qout)
{
  __shared__ __align__(16) float sf[16][DIM];
  const int r0 = blockIdx.x * 16, t = threadIdx.x;
  for (int r = 0; r < 16; ++r) sf[r][t] = features[(size_t)(r0+r)*DIM + t];
  __syncthreads();
  float acc[16];
  const float bqv = bq[t];
  #pragma unroll
  for (int r = 0; r < 16; ++r) acc[r] = bqv;
  for (int d = 0; d < DIM; d += 4) {
    float w0 = wq[(d+0)*DIM+t], w1 = wq[(d+1)*DIM+t];
    float w2 = wq[(d+2)*DIM+t], w3v = wq[(d+3)*DIM+t];
    #pragma unroll
    for (int r = 0; r < 16; ++r) {
      float4 f4 = *(const float4*)&sf[r][d];
      acc[r] = fmaf(f4.x, w0, acc[r]); acc[r] = fmaf(f4.y, w1, acc[r]);
      acc[r] = fmaf(f4.z, w2, acc[r]); acc[r] = fmaf(f4.w, w3v, acc[r]);
    }
  }
  #pragma unroll
  for (int r = 0; r < 16; ++r) qout[(size_t)(r0+r)*DIM + t] = acc[r];
}

// ---------------------------------------------------------------------------
// Kernel 4: fused per-point pipeline. No F staging (streamed from L1/L2),
// h2-GEMM on MFMA. LDS ~30.6KB -> 4 blocks/CU.
// ---------------------------------------------------------------------------
__global__ __launch_bounds__(256, 4) void fused_kernel(
    const float* __restrict__ features,
    float* __restrict__ qctx,                       // d_out: q in, ctx out
    const int*    __restrict__ knn_idx,
    const __half* __restrict__ knn_dist,
    const u16* __restrict__ wkT2, const u16* __restrict__ w3Tf,
    const u16* __restrict__ w3f2, const u16* __restrict__ wvB2,
    const u16* __restrict__ w2frag,
    const float* __restrict__ de_w1, const float* __restrict__ de_b1,
    const float* __restrict__ de_b2, const float* __restrict__ de_b3,
    const float* __restrict__ bk,    const float* __restrict__ bv)
{
  __shared__ __align__(16) unsigned s_h2_32[KNNK*64]; // 16KB h2 f16 pairs (swizzled)
  __shared__ __align__(16) float    s_gm[2048];       // 8KB: ghb f16[8][256] -> m f32[8][256]
  __shared__ __align__(16) float    s_d[1024];        // 4KB: w3gb f16(2KB)+sc f32(2KB) -> ah2p u32(2KB)
  __shared__ __align__(16) float    s_aT[KNNK*NHEAD]; // 2KB attn f32 [kk][h]
  __shared__ int   s_nidx[KNNK];
  __shared__ float s_ndist[KNNK];
  __shared__ float s_sb[NHEAD];

  u16*      s_ghb  = (u16*)s_gm;          // f16 [8][256]
  u16*      s_w3gb = (u16*)s_d;           // f16 [8][128]
  float*    s_sc   = s_d + 512;           // f32 [8][64]
  unsigned* s_ah2p = (unsigned*)s_d;      // u32 [64][8]  (after P6)
  float*    s_m    = s_gm;                // f32 [8][256] (after P5)

  const int bp = blockIdx.x;
  const int b  = bp >> 11;
  const int t  = threadIdx.x;
  const float* featB = features + (size_t)b * NPOINTS * DIM;
  const float* qrow  = qctx + (size_t)bp * DIM;     // wave-uniform -> s_load

  // ---- P0 ----
  if (t < KNNK) {
    s_nidx[t]  = knn_idx[(size_t)bp*KNNK + t];
    s_ndist[t] = __half2float(knn_dist[(size_t)bp*KNNK + t]);
  }
  __syncthreads();

  // ---- phase A: g-fold (P2) + sb=q.bk ----
  {
    const unsigned* wk2 = (const unsigned*)wkT2;
    #pragma unroll
    for (int h = 0; h < NHEAD; ++h) {
      float a = 0.f;
      #pragma unroll
      for (int dg = 0; dg < 16; ++dg) {
        const int d2 = h*16 + dg;
        a = fdot2f(wk2[d2*256 + t], pkh2(qrow[2*d2], qrow[2*d2+1]), a);
      }
      s_ghb[h*256 + t] = f2h(a);
    }
    if (t < NHEAD) {
      float s = 0.f;
      for (int d = 0; d < HDIM; ++d) s = fmaf(bk[t*HDIM+d], qrow[t*HDIM+d], s);
      s_sb[t] = s;
    }
  }
  __syncthreads();

  // ---- phase B: w3g-fold + sb += b3.g  and  h2 via MFMA ----
  {
    const int j = t & 127, h0 = (t >> 7) * 4;
    float a0=0.f, a1=0.f, a2=0.f, a3=0.f;
    const uint4* w3r = (const uint4*)(w3Tf + (size_t)j*256);
    #pragma unroll 4
    for (int c8 = 0; c8 < 32; ++c8) {
      uint4 wv4 = w3r[c8];
      uint4 gv;
      gv = *(const uint4*)(s_ghb + (h0+0)*256 + c8*8);
      a0 = fdot2f(wv4.x, gv.x, a0); a0 = fdot2f(wv4.y, gv.y, a0);
      a0 = fdot2f(wv4.z, gv.z, a0); a0 = fdot2f(wv4.w, gv.w, a0);
      gv = *(const uint4*)(s_ghb + (h0+1)*256 + c8*8);
      a1 = fdot2f(wv4.x, gv.x, a1); a1 = fdot2f(wv4.y, gv.y, a1);
      a1 = fdot2f(wv4.z, gv.z, a1); a1 = fdot2f(wv4.w, gv.w, a1);
      gv = *(const uint4*)(s_ghb + (h0+2)*256 + c8*8);
      a2 = fdot2f(wv4.x, gv.x, a2); a2 = fdot2f(wv4.y, gv.y, a2);
      a2 = fdot2f(wv4.z, gv.z, a2); a2 = fdot2f(wv4.w, gv.w, a2);
      gv = *(const uint4*)(s_ghb + (h0+3)*256 + c8*8);
      a3 = fdot2f(wv4.x, gv.x, a3); a3 = fdot2f(wv4.y, gv.y, a3);
      a3 = fdot2f(wv4.z, gv.z, a3); a3 = fdot2f(wv4.w, gv.w, a3);
    }
    s_w3gb[(h0+0)*128 + j] = f2h(a0);
    s_w3gb[(h0+1)*128 + j] = f2h(a1);
    s_w3gb[(h0+2)*128 + j] = f2h(a2);
    s_w3gb[(h0+3)*128 + j] = f2h(a3);
    if (t < NHEAD) {
      float s = s_sb[t];
      const uint4* gr = (const uint4*)(s_ghb + t*256);
      for (int c8 = 0; c8 < 32; ++c8) {
        uint4 gv = gr[c8];
        float4 bA = *(const float4*)&de_b3[c8*8];
        float4 bB = *(const float4*)&de_b3[c8*8+4];
        float2 p;
        p = uph2(gv.x); s = fmaf(p.x, bA.x, s); s = fmaf(p.y, bA.y, s);
        p = uph2(gv.y); s = fmaf(p.x, bA.z, s); s = fmaf(p.y, bA.w, s);
        p = uph2(gv.z); s = fmaf(p.x, bB.x, s); s = fmaf(p.y, bB.y, s);
        p = uph2(gv.w); s = fmaf(p.x, bB.z, s); s = fmaf(p.y, bB.w, s);
      }
      s_sb[t] = s;
    }
    // h2[64][128] = relu(h1 @ w2 + b2) via v_mfma_f32_16x16x32_f16.
    // A lane l = h1[m=l&15][k-slot], B lane l = w2[k-slot][n=l&15]; same
    // k-slot map on both sides => product correct for any slot bijection.
    // D: col = lane&15, row = (lane>>4)*4 + reg (verified layout).
    {
      const int w = t >> 6, l = t & 63;
      const int lm = l & 15, lg = l >> 4;
      const float dd = s_ndist[w*16 + lm];
      f16x8 af[2];
      #pragma unroll
      for (int ks = 0; ks < 2; ++ks) {
        const int i0 = ks*32 + lg*8;
        float4 w1a = *(const float4*)&de_w1[i0];
        float4 w1b = *(const float4*)&de_w1[i0+4];
        float4 b1a = *(const float4*)&de_b1[i0];
        float4 b1b = *(const float4*)&de_b1[i0+4];
        af[ks][0] = (_Float16)fmaxf(fmaf(dd, w1a.x, b1a.x), 0.f);
        af[ks][1] = (_Float16)fmaxf(fmaf(dd, w1a.y, b1a.y), 0.f);
        af[ks][2] = (_Float16)fmaxf(fmaf(dd, w1a.z, b1a.z), 0.f);
        af[ks][3] = (_Float16)fmaxf(fmaf(dd, w1a.w, b1a.w), 0.f);
        af[ks][4] = (_Float16)fmaxf(fmaf(dd, w1b.x, b1b.x), 0.f);
        af[ks][5] = (_Float16)fmaxf(fmaf(dd, w1b.y, b1b.y), 0.f);
        af[ks][6] = (_Float16)fmaxf(fmaf(dd, w1b.z, b1b.z), 0.f);
        af[ks][7] = (_Float16)fmaxf(fmaf(dd, w1b.w, b1b.w), 0.f);
      }
      f32x4 cacc[8];
      #pragma unroll
      for (int n = 0; n < 8; ++n) {
        float b2j = de_b2[n*16 + lm];
        f32x4 c = {b2j, b2j, b2j, b2j};
        f16x8 bf0, bf1;
        uint4 r0 = *(const uint4*)(w2frag + (((n*2+0)*64 + l)<<3));
        uint4 r1 = *(const uint4*)(w2frag + (((n*2+1)*64 + l)<<3));
        __builtin_memcpy(&bf0, &r0, 16);
        __builtin_memcpy(&bf1, &r1, 16);
        c = __builtin_amdgcn_mfma_f32_16x16x32_f16(af[0], bf0, c, 0, 0, 0);
        c = __builtin_amdgcn_mfma_f32_16x16x32_f16(af[1], bf1, c, 0, 0, 0);
        cacc[n] = c;
      }
      u16* h2w = (u16*)s_h2_32;
      #pragma unroll
      for (int n = 0; n < 8; ++n) {
        const int j = n*16 + lm;
        #pragma unroll
        for (int r = 0; r < 4; ++r) {
          const int kk = w*16 + lg*4 + r;
          h2w[kk*128 + (((j>>3)^(kk&15))<<3) + (j&7)] = f2h(fmaxf(cacc[n][r], 0.f));
        }
      }
    }
  }
  __syncthreads();

  // ---- P5: scores[h][kk] = (F.g + h2.w3g + sb[h]) * SCALE ----
  // F streamed from global (L1 row-window), packed to f16 pairs for fdot2.
  {
    const int kk = t & 63, ha = t >> 6, hb = ha + 4;
    const int kh = kk & 15;
    float accA = 0.f, accB = 0.f;
    const float* Fr = featB + (size_t)s_nidx[kk]*DIM;
    const uint4* GA = (const uint4*)(s_ghb + ha*256);
    const uint4* GB = (const uint4*)(s_ghb + hb*256);
    #pragma unroll 2
    for (int c8 = 0; c8 < 32; ++c8) {
      float4 f0 = *(const float4*)&Fr[c8*8];
      float4 f1 = *(const float4*)&Fr[c8*8+4];
      unsigned fp0 = pkh2(f0.x, f0.y), fp1 = pkh2(f0.z, f0.w);
      unsigned fp2 = pkh2(f1.x, f1.y), fp3 = pkh2(f1.z, f1.w);
      uint4 ga = GA[c8], gb = GB[c8];
      accA = fdot2f(fp0, ga.x, accA); accA = fdot2f(fp1, ga.y, accA);
      accA = fdot2f(fp2, ga.z, accA); accA = fdot2f(fp3, ga.w, accA);
      accB = fdot2f(fp0, gb.x, accB); accB = fdot2f(fp1, gb.y, accB);
      accB = fdot2f(fp2, gb.z, accB); accB = fdot2f(fp3, gb.w, accB);
    }
    const uint4* Hr = (const uint4*)(s_h2_32 + kk*64);
    const uint4* WA = (const uint4*)(s_w3gb + ha*128);
    const uint4* WB = (const uint4*)(s_w3gb + hb*128);
    #pragma unroll 4
    for (int j8 = 0; j8 < 16; ++j8) {
      uint4 hv = Hr[j8 ^ kh];
      uint4 wa = WA[j8], wb = WB[j8];
      accA = fdot2f(hv.x, wa.x, accA); accA = fdot2f(hv.y, wa.y, accA);
      accA = fdot2f(hv.z, wa.z, accA); accA = fdot2f(hv.w, wa.w, accA);
      accB = fdot2f(hv.x, wb.x, accB); accB = fdot2f(hv.y, wb.y, accB);
      accB = fdot2f(hv.z, wb.z, accB); accB = fdot2f(hv.w, wb.w, accB);
    }
    s_sc[ha*64 + kk] = (accA + s_sb[ha]) * SCALE_F;
    s_sc[hb*64 + kk] = (accB + s_sb[hb]) * SCALE_F;
  }
  __syncthreads();

  // ---- P6: softmax over K=64 per head; attn stays f32 ----
  {
    const int h = t >> 5, k2 = t & 31;
    float v0 = s_sc[h*64 + k2], v1 = s_sc[h*64 + k2 + 32];
    float mx = fmaxf(v0, v1);
    #pragma unroll
    for (int off = 16; off > 0; off >>= 1) mx = fmaxf(mx, __shfl_xor(mx, off, 32));
    float e0 = expf(v0 - mx), e1 = expf(v1 - mx);
    float sm = e0 + e1;
    #pragma unroll
    for (int off = 16; off > 0; off >>= 1) sm += __shfl_xor(sm, off, 32);
    float inv = 1.f / sm;
    s_aT[k2*NHEAD + h]      = e0 * inv;
    s_aT[(k2+32)*NHEAD + h] = e1 * inv;
  }
  __syncthreads();

  // ---- P8a: ah2 = attn @ h2, output packed f16 j-pairs [j2][h] ----
  {
    const int jj2 = t & 63, hp = t >> 6;
    const int j = jj2*2;
    float a00=0.f, a01=0.f, a10=0.f, a11=0.f;
    #pragma unroll 4
    for (int kk = 0; kk < KNNK; ++kk) {
      unsigned hpw = s_h2_32[kk*64 + (((j>>3)^(kk&15))<<2) + ((j&7)>>1)];
      float2 hv = uph2(hpw);
      float2 av = *(const float2*)&s_aT[kk*NHEAD + hp*2];
      a00 = fmaf(av.x, hv.x, a00); a01 = fmaf(av.x, hv.y, a01);
      a10 = fmaf(av.y, hv.x, a10); a11 = fmaf(av.y, hv.y, a11);
    }
    s_ah2p[jj2*8 + hp*2]     = pkh2(a00, a01);
    s_ah2p[jj2*8 + hp*2 + 1] = pkh2(a10, a11);
  }
  __syncthreads();

  // ---- P8b: m[h][c] = attn@F + ah2@w3 + b3 (f32); F from global (coalesced) ----
  {
    const int h = t >> 5, ct = t & 31;
    float mac[8];
    float4 b3a = *(const float4*)&de_b3[ct*8];
    float4 b3b = *(const float4*)&de_b3[ct*8+4];
    mac[0]=b3a.x; mac[1]=b3a.y; mac[2]=b3a.z; mac[3]=b3a.w;
    mac[4]=b3b.x; mac[5]=b3b.y; mac[6]=b3b.z; mac[7]=b3b.w;
    #pragma unroll 2
    for (int kk = 0; kk < KNNK; ++kk) {
      const float* Fr = featB + (size_t)s_nidx[kk]*DIM + ct*8;
      float4 f0 = *(const float4*)Fr;
      float4 f1 = *(const float4*)(Fr+4);
      float a = s_aT[kk*NHEAD + h];
      mac[0] = fmaf(a, f0.x, mac[0]); mac[1] = fmaf(a, f0.y, mac[1]);
      mac[2] = fmaf(a, f0.z, mac[2]); mac[3] = fmaf(a, f0.w, mac[3]);
      mac[4] = fmaf(a, f1.x, mac[4]); mac[5] = fmaf(a, f1.y, mac[5]);
      mac[6] = fmaf(a, f1.z, mac[6]); mac[7] = fmaf(a, f1.w, mac[7]);
    }
    const unsigned* w3_32 = (const unsigned*)w3f2;
    #pragma unroll 2
    for (int jj2 = 0; jj2 < 64; ++jj2) {
      unsigned ap = s_ah2p[jj2*8 + h];
      const uint4* wr = (const uint4*)(w3_32 + jj2*256 + ct*8);
      uint4 w0 = wr[0], w1 = wr[1];
      mac[0] = fdot2f(w0.x, ap, mac[0]); mac[1] = fdot2f(w0.y, ap, mac[1]);
      mac[2] = fdot2f(w0.z, ap, mac[2]); mac[3] = fdot2f(w0.w, ap, mac[3]);
      mac[4] = fdot2f(w1.x, ap, mac[4]); mac[5] = fdot2f(w1.y, ap, mac[5]);
      mac[6] = fdot2f(w1.z, ap, mac[6]); mac[7] = fdot2f(w1.w, ap, mac[7]);
    }
    *(float4*)&s_m[h*256 + ct*8]     = make_float4(mac[0], mac[1], mac[2], mac[3]);
    *(float4*)&s_m[h*256 + ct*8 + 4] = make_float4(mac[4], mac[5], mac[6], mac[7]);
  }
  __syncthreads();

  // ---- P9: ctx[t] = m[h] . wv[:, t] + bv[t]  (t = h*32+d) ----
  {
    const int h = t >> 5;
    const float* mr = s_m + h*256;
    const unsigned* wv_32 = (const unsigned*)wvB2;
    float acc = bv[t];
    #pragma unroll 4
    for (int c4 = 0; c4 < 64; ++c4) {
      float4 m4 = *(const float4*)(mr + c4*4);
      float2 wa = uph2(wv_32[(c4*2)*256 + t]);
      float2 wb = uph2(wv_32[(c4*2+1)*256 + t]);
      acc = fmaf(wa.x, m4.x, acc); acc = fmaf(wa.y, m4.y, acc);
      acc = fmaf(wb.x, m4.z, acc); acc = fmaf(wb.y, m4.w, acc);
    }
    qctx[(size_t)bp*DIM + t] = acc;
  }
}

// ---------------------------------------------------------------------------
// Kernel 5: batched tail, 16 rows/block (unchanged).
// ---------------------------------------------------------------------------
__global__ __launch_bounds__(256) void se_kernel(
    const float* __restrict__ features,
    const float* __restrict__ wo,    const float* __restrict__ bo,
    const float* __restrict__ se_w1, const float* __restrict__ se_b1,
    const float* __restrict__ ln_g,  const float* __restrict__ ln_b,
    const float* __restrict__ se_w2, const float* __restrict__ se_b2,
    float* io)
{
  __shared__ __align__(16) float sA[16][DIM];
  __shared__ __align__(16) float sB[16][DIM];
  __shared__ __align__(16) float sAtt[16][DIM];
  __shared__ float s_mu[16], s_rs[16];
  const int r0 = blockIdx.x * 16, t = threadIdx.x;

  for (int r = 0; r < 16; ++r) {
    sA[r][t] = io[(size_t)(r0+r)*DIM + t];
    sB[r][t] = features[(size_t)(r0+r)*DIM + t];
  }
  __syncthreads();

  {
    float acc[16];
    const float bov = bo[t];
    #pragma unroll
    for (int r = 0; r < 16; ++r) acc[r] = bov;
    for (int d = 0; d < DIM; d += 4) {
      float w0 = wo[(d+0)*DIM+t], w1 = wo[(d+1)*DIM+t];
      float w2 = wo[(d+2)*DIM+t], w3v = wo[(d+3)*DIM+t];
      #pragma unroll
      for (int r = 0; r < 16; ++r) {
        float4 f4 = *(const float4*)&sA[r][d];
        acc[r] = fmaf(f4.x, w0, acc[r]); acc[r] = fmaf(f4.y, w1, acc[r]);
        acc[r] = fmaf(f4.z, w2, acc[r]); acc[r] = fmaf(f4.w, w3v, acc[r]);
      }
    }
    #pragma unroll
    for (int r = 0; r < 16; ++r) sAtt[r][t] = acc[r];
  }
  __syncthreads();

  {
    float acc[16];
    const float b1v = se_b1[t];
    #pragma unroll
    for (int r = 0; r < 16; ++r) acc[r] = b1v;
    for (int d = 0; d < DIM; d += 4) {
      float w0 = se_w1[(d+0)*DIM+t], w1 = se_w1[(d+1)*DIM+t];
      float w2 = se_w1[(d+2)*DIM+t], w3v = se_w1[(d+3)*DIM+t];
      #pragma unroll
      for (int r = 0; r < 16; ++r) {
        float4 f4 = *(const float4*)&sB[r][d];
        acc[r] = fmaf(f4.x, w0, acc[r]); acc[r] = fmaf(f4.y, w1, acc[r]);
        acc[r] = fmaf(f4.z, w2, acc[r]); acc[r] = fmaf(f4.w, w3v, acc[r]);
      }
    }
    for (int d = 0; d < DIM; d += 4) {
      float w0 = se_w1[(DIM+d+0)*DIM+t], w1 = se_w1[(DIM+d+1)*DIM+t];
      float w2 = se_w1[(DIM+d+2)*DIM+t], w3v = se_w1[(DIM+d+3)*DIM+t];
      #pragma unroll
      for (int r = 0; r < 16; ++r) {
        float4 f4 = *(const float4*)&sAtt[r][d];
        acc[r] = fmaf(f4.x, w0, acc[r]); acc[r] = fmaf(f4.y, w1, acc[r]);
        acc[r] = fmaf(f4.z, w2, acc[r]); acc[r] = fmaf(f4.w, w3v, acc[r]);
      }
    }
    __syncthreads();
    #pragma unroll
    for (int r = 0; r < 16; ++r) sA[r][t] = acc[r];
  }
  __syncthreads();

  {
    const int w = t >> 6, lane = t & 63;
    for (int i = 0; i < 4; ++i) {
      const int r = w*4 + i;
      float v0 = sA[r][lane], v1 = sA[r][lane+64];
      float v2 = sA[r][lane+128], v3 = sA[r][lane+192];
      float s1 = v0+v1+v2+v3;
      float s2 = v0*v0 + v1*v1 + v2*v2 + v3*v3;
      #pragma unroll
      for (int off = 32; off > 0; off >>= 1) {
        s1 += __shfl_xor(s1, off);
        s2 += __shfl_xor(s2, off);
      }
      if (lane == 0) {
        float mu = s1 * (1.f/256.f);
        s_mu[r] = mu;
        s_rs[r] = 1.f / sqrtf(s2 * (1.f/256.f) - mu*mu + 1e-5f);
      }
    }
  }
  __syncthreads();

  {
    const float lg = ln_g[t], lb = ln_b[t];
    #pragma unroll
    for (int r = 0; r < 16; ++r)
      sB[r][t] = fmaxf(fmaf((sA[r][t] - s_mu[r]) * s_rs[r], lg, lb), 0.f);
  }
  __syncthreads();

  {
    float acc[16];
    const float b2v = se_b2[t];
    #pragma unroll
    for (int r = 0; r < 16; ++r) acc[r] = b2v;
    for (int d = 0; d < DIM; d += 4) {
      float w0 = se_w2[(d+0)*DIM+t], w1 = se_w2[(d+1)*DIM+t];
      float w2 = se_w2[(d+2)*DIM+t], w3v = se_w2[(d+3)*DIM+t];
      #pragma unroll
      for (int r = 0; r < 16; ++r) {
        float4 f4 = *(const float4*)&sB[r][d];
        acc[r] = fmaf(f4.x, w0, acc[r]); acc[r] = fmaf(f4.y, w1, acc[r]);
        acc[r] = fmaf(f4.z, w2, acc[r]); acc[r] = fmaf(f4.w, w3v, acc[r]);
      }
    }
    #pragma unroll
    for (int r = 0; r < 16; ++r) io[(size_t)(r0+r)*DIM + t] = acc[r];
  }
}

extern "C" void kernel_launch(void* const* d_in, const int* in_sizes, int n_in,
                              void* d_out, int out_size, void* d_ws, size_t ws_size,
                              hipStream_t stream) {
  const float* features = (const float*)d_in[0];
  const float* xyz      = (const float*)d_in[1];
  const float* de_w1 = (const float*)d_in[2];
  const float* de_b1 = (const float*)d_in[3];
  const float* de_w2 = (const float*)d_in[4];
  const float* de_b2 = (const float*)d_in[5];
  const float* de_w3 = (const float*)d_in[6];
  const float* de_b3 = (const float*)d_in[7];
  const float* wq = (const float*)d_in[8];
  const float* bq = (const float*)d_in[9];
  const float* wk = (const float*)d_in[10];
  const float* bk = (const float*)d_in[11];
  const float* wv = (const float*)d_in[12];
  const float* bv = (const float*)d_in[13];
  const float* wo = (const float*)d_in[14];
  const float* bo = (const float*)d_in[15];
  const float* se_w1 = (const float*)d_in[16];
  const float* se_b1 = (const float*)d_in[17];
  const float* ln_g  = (const float*)d_in[18];
  const float* ln_b  = (const float*)d_in[19];
  const float* se_w2 = (const float*)d_in[20];
  const float* se_b2 = (const float*)d_in[21];

  // ws layout (1.9375 MB total):
  //   [0,1MB)    knn_idx int[4096][64]
  //   [+512KB)   knn_dist f16[4096][64]
  //   [+128KB)   wkT2   f16 pairs
  //   [+64KB)    w3Tf   f16 [j][c]
  //   [+64KB)    w3f2   f16 pairs
  //   [+128KB)   wvB2   f16 pairs
  //   [+16KB)    w2frag f16 MFMA fragments
  char* wsb = (char*)d_ws;
  int*    knn_idx  = (int*)wsb;
  __half* knn_dist = (__half*)(wsb + (1u<<20));
  u16* wkT2   = (u16*)(wsb + 1536u*1024u);
  u16* w3Tf   = (u16*)(wsb + 1536u*1024u + 128u*1024u);
  u16* w3f2   = (u16*)(wsb + 1536u*1024u + 192u*1024u);
  u16* wvB2   = (u16*)(wsb + 1536u*1024u + 256u*1024u);
  u16* w2frag = (u16*)(wsb + 1536u*1024u + 384u*1024u);

  knn_kernel<<<NROWS, 256, 0, stream>>>(xyz, knn_idx, knn_dist);
  prep_kernel<<<800, 256, 0, stream>>>(wk, de_w3, wv, de_w2,
                                       wkT2, w3Tf, w3f2, wvB2, w2frag);
  qproj_kernel<<<NROWS/16, 256, 0, stream>>>(features, wq, bq, (float*)d_out);
  fused_kernel<<<NROWS, 256, 0, stream>>>(
      features, (float*)d_out, knn_idx, knn_dist,
      wkT2, w3Tf, w3f2, wvB2, w2frag,
      de_w1, de_b1, de_b2, de_b3, bk, bv);
  se_kernel<<<NROWS/16, 256, 0, stream>>>(
      features, wo, bo, se_w1, se_b1, ln_g, ln_b, se_w2, se_b2, (float*)d_out);
}

// Round 4
// 356.496 us; speedup vs baseline: 1.3815x; 1.3815x over previous
//
#include <hip/hip_runtime.h>
#include <hip/hip_bf16.h>
#include <hip/hip_fp16.h>

#define NPOINTS 2048
#define BATCH   2
#define DIM     256
#define D2      128
#define D4      64
#define NHEAD   8
#define HDIM    32
#define KNNK    64
#define NROWS   (BATCH*NPOINTS)
#define SCALE_F 0.17677669529663687f

typedef unsigned short u16;
typedef _Float16 f16x8 __attribute__((ext_vector_type(8)));
typedef float f32x4 __attribute__((ext_vector_type(4)));

__device__ __forceinline__ u16 f2h(float f) {
  __half h = __float2half(f); u16 r; __builtin_memcpy(&r, &h, 2); return r;
}
__device__ __forceinline__ unsigned pkh2(float a, float b) {
  __half2 h = __floats2half2_rn(a, b); unsigned r; __builtin_memcpy(&r, &h, 4); return r;
}
__device__ __forceinline__ float2 uph2(unsigned u) {
  __half2 h; __builtin_memcpy(&h, &u, 4); return __half22float2(h);
}

#if __has_builtin(__builtin_amdgcn_fdot2)
typedef _Float16 hv2_t __attribute__((ext_vector_type(2)));
__device__ __forceinline__ float fdot2f(unsigned a, unsigned b, float c) {
  hv2_t x, y; __builtin_memcpy(&x, &a, 4); __builtin_memcpy(&y, &b, 4);
  return __builtin_amdgcn_fdot2(x, y, c, false);
}
#else
__device__ __forceinline__ float fdot2f(unsigned a, unsigned b, float c) {
  float2 x = uph2(a), y = uph2(b);
  return fmaf(x.x, y.x, fmaf(x.y, y.y, c));
}
#endif

// ---------------------------------------------------------------------------
// Kernel 1: exact KNN (64 smallest of 2048) per point. Distances stored f16.
// ---------------------------------------------------------------------------
__global__ __launch_bounds__(256) void knn_kernel(
    const float* __restrict__ xyz,
    int*    __restrict__ knn_idx,
    __half* __restrict__ knn_dist)
{
  __shared__ float dist[NPOINTS];
  __shared__ unsigned hist[256];
  __shared__ unsigned sh_sel, sh_below;

  const int bp = blockIdx.x;
  const int b  = bp >> 11;
  const int n  = bp & (NPOINTS - 1);
  const int t  = threadIdx.x;
  const float* P = xyz + (size_t)b * NPOINTS * 3;

  const float qx = P[n*3+0], qy = P[n*3+1], qz = P[n*3+2];
  const float r2n = qx*qx + qy*qy + qz*qz;
  for (int m = t; m < NPOINTS; m += 256) {
    float x = P[m*3+0], y = P[m*3+1], z = P[m*3+2];
    float r2m = x*x + y*y + z*z;
    float dt  = x*qx + y*qy + z*qz;
    float sq  = r2n + r2m - 2.f*dt;
    sq = fmaxf(sq, 0.f);
    dist[m] = (sq > 0.f) ? sqrtf(sq) : 0.f;
  }
  __syncthreads();

  unsigned prefix = 0u;
  int k_need = KNNK;
  for (int pass = 0; pass < 4; ++pass) {
    const int shift = 24 - pass*8;
    hist[t] = 0u;
    __syncthreads();
    for (int m = t; m < NPOINTS; m += 256) {
      unsigned bits = __float_as_uint(dist[m]);
      if (((bits >> shift) >> 8) == prefix)
        atomicAdd(&hist[(bits >> shift) & 255u], 1u);
    }
    __syncthreads();
    if (t < 64) {
      unsigned s0 = hist[t*4+0], s1 = hist[t*4+1], s2 = hist[t*4+2], s3 = hist[t*4+3];
      unsigned lsum = s0 + s1 + s2 + s3;
      unsigned scan = lsum;
      #pragma unroll
      for (int off = 1; off < 64; off <<= 1) {
        unsigned o = __shfl_up(scan, off);
        if (t >= off) scan += o;
      }
      unsigned excl = scan - lsum;
      unsigned kk = (unsigned)k_need;
      if (excl < kk && kk <= excl + lsum) {
        unsigned below = excl; int bin = t*4;
        if (kk > below + s0) { below += s0; bin++;
          if (kk > below + s1) { below += s1; bin++;
            if (kk > below + s2) { below += s2; bin++; } } }
        sh_sel = (unsigned)bin; sh_below = below;
      }
    }
    __syncthreads();
    prefix = (prefix << 8) | sh_sel;
    k_need -= (int)sh_below;
    __syncthreads();
  }
  const unsigned Tbits = prefix;
  const int base = KNNK - k_need;

  if (t < 64) {
    int*    oi = knn_idx  + (size_t)bp * KNNK;
    __half* od = knn_dist + (size_t)bp * KNNK;
    int taken = 0;
    for (int c = 0; c < NPOINTS/64; ++c) {
      int m = c*64 + t;
      float dv = dist[m];
      bool lt = (__float_as_uint(dv) < Tbits);
      unsigned long long msk = __ballot(lt);
      int off = __popcll(msk & ((1ull << t) - 1ull));
      if (lt) { oi[taken+off] = m; od[taken+off] = __float2half(dv); }
      taken += __popcll(msk);
    }
    int eq = 0;
    for (int c = 0; c < NPOINTS/64 && eq < k_need; ++c) {
      int m = c*64 + t;
      float dv = dist[m];
      bool e = (__float_as_uint(dv) == Tbits);
      unsigned long long msk = __ballot(e);
      int off = __popcll(msk & ((1ull << t) - 1ull));
      if (e && (eq + off) < k_need) { oi[base+eq+off] = m; od[base+eq+off] = __float2half(dv); }
      eq += __popcll(msk);
    }
  }
}

// ---------------------------------------------------------------------------
// Kernel 2: elementwise weight repack (f16) into ws.
//   wkT2   [d2][c][2]  pairs over d   (g-fold)
//   wvB2   [c2][d][2]  pairs over c   (P9')
//   w2frag MFMA B-fragments of de_w2  (h2 MFMA)
// ---------------------------------------------------------------------------
__global__ __launch_bounds__(256) void prep_kernel(
    const float* __restrict__ wk, const float* __restrict__ wv,
    const float* __restrict__ de_w2,
    u16* __restrict__ wkT2, u16* __restrict__ wvB2, u16* __restrict__ w2frag)
{
  int tid = blockIdx.x*256 + threadIdx.x;
  if (tid < 65536) {
    int d = tid >> 8, c = tid & 255;
    wkT2[(d>>1)*512 + c*2 + (d&1)] = f2h(wk[c*DIM + d]);
  } else if (tid < 131072) {
    int o = tid - 65536; int c = o >> 8, d = o & 255;
    wvB2[(c>>1)*512 + d*2 + (c&1)] = f2h(wv[c*DIM + d]);
  } else if (tid < 139264) {
    int o = tid - 131072;            // 0..8191
    int e = o & 7, l = (o >> 3) & 63, ks = (o >> 9) & 1, n = o >> 10;
    int i = ks*32 + ((l >> 4) << 3) + e;
    int j = n*16 + (l & 15);
    w2frag[o] = f2h(de_w2[i*D2 + j]);
  }
}

// ---------------------------------------------------------------------------
// Kernel 2b: weight-fold GEMMs.
//   w3k = de_w3 @ wk  -> w3kp f16 [h][j][d-in-h]   (per-point w3g fold)
//   w3v = de_w3 @ wv  -> w3vp f16 [j2][t][2]       (P9')
//   bkb3k[d] = bk[d] + (b3 @ wk)[d]                (score bias)
//   cb[t]    = bv[t] + (b3 @ wv)[t]                (ctx bias)
// ---------------------------------------------------------------------------
__global__ __launch_bounds__(256) void prep2_kernel(
    const float* __restrict__ de_w3, const float* __restrict__ de_b3,
    const float* __restrict__ wk,    const float* __restrict__ wv,
    const float* __restrict__ bk,    const float* __restrict__ bv,
    u16* __restrict__ w3kp, u16* __restrict__ w3vp,
    float* __restrict__ bkb3k, float* __restrict__ cbias)
{
  const int j = blockIdx.x, t = threadIdx.x;
  float ak = 0.f, av = 0.f;
  if (j < D2) {
    const float* wrow = de_w3 + (size_t)j*DIM;
    #pragma unroll 4
    for (int c = 0; c < DIM; ++c) {
      float w = wrow[c];
      ak = fmaf(w, wk[c*DIM + t], ak);
      av = fmaf(w, wv[c*DIM + t], av);
    }
    w3kp[(((t>>5)*D2 + j)<<5) + (t&31)] = f2h(ak);
    w3vp[(j>>1)*512 + t*2 + (j&1)]      = f2h(av);
  } else {
    #pragma unroll 4
    for (int c = 0; c < DIM; ++c) {
      float w = de_b3[c];
      ak = fmaf(w, wk[c*DIM + t], ak);
      av = fmaf(w, wv[c*DIM + t], av);
    }
    bkb3k[t] = bk[t] + ak;
    cbias[t] = bv[t] + av;
  }
}

// ---------------------------------------------------------------------------
// Kernel 3: batched q projection, 16 rows/block. q -> d_out (scratch).
// ---------------------------------------------------------------------------
__global__ __launch_bounds__(256) void qproj_kernel(
    const float* __restrict__ features, const float* __restrict__ wq,
    const float* __restrict__ bq, float* __restrict__ qout)
{
  __shared__ __align__(16) float sf[16][DIM];
  const int r0 = blockIdx.x * 16, t = threadIdx.x;
  for (int r = 0; r < 16; ++r) sf[r][t] = features[(size_t)(r0+r)*DIM + t];
  __syncthreads();
  float acc[16];
  const float bqv = bq[t];
  #pragma unroll
  for (int r = 0; r < 16; ++r) acc[r] = bqv;
  for (int d = 0; d < DIM; d += 4) {
    float w0 = wq[(d+0)*DIM+t], w1 = wq[(d+1)*DIM+t];
    float w2 = wq[(d+2)*DIM+t], w3v = wq[(d+3)*DIM+t];
    #pragma unroll
    for (int r = 0; r < 16; ++r) {
      float4 f4 = *(const float4*)&sf[r][d];
      acc[r] = fmaf(f4.x, w0, acc[r]); acc[r] = fmaf(f4.y, w1, acc[r]);
      acc[r] = fmaf(f4.z, w2, acc[r]); acc[r] = fmaf(f4.w, w3v, acc[r]);
    }
  }
  #pragma unroll
  for (int r = 0; r < 16; ++r) qout[(size_t)(r0+r)*DIM + t] = acc[r];
}

// ---------------------------------------------------------------------------
// Kernel 4: fused per-point pipeline.
//   phase1: g-fold + w3g (via w3k) + sb + h2-MFMA     (one barrier)
//   P5':    scores, 4-lane-split F slices (coalesced) (one barrier)
//   P6:     softmax                                    (one barrier)
//   P8a+mF: ah2 = attn@h2 ; mF = attn@F (prefetch)     (one barrier)
//   P9':    ctx = mF.wv + ah2.w3v + cb
// ---------------------------------------------------------------------------
__global__ __launch_bounds__(256, 4) void fused_kernel(
    const float* __restrict__ features,
    float* __restrict__ qctx,                       // d_out: q in, ctx out
    const int*    __restrict__ knn_idx,
    const __half* __restrict__ knn_dist,
    const u16* __restrict__ wkT2, const u16* __restrict__ wvB2,
    const u16* __restrict__ w2frag,
    const u16* __restrict__ w3kp, const u16* __restrict__ w3vp,
    const float* __restrict__ de_w1, const float* __restrict__ de_b1,
    const float* __restrict__ de_b2,
    const float* __restrict__ bkb3k, const float* __restrict__ cbias)
{
  __shared__ __align__(16) unsigned s_h2_32[KNNK*64];  // 16KB h2 f16 pairs (swizzled)
  __shared__ __align__(16) float    s_m[2048];         // 8KB mF f32 [8][256]
  __shared__ __align__(16) unsigned s_gp[8*4*36];      // 4.5KB g f16 pairs, stride-36 pad
  __shared__ __align__(16) float    s_d[1024];         // w3gb f16(2KB)+sc f32(2KB) -> ah2p u32(2KB)
  __shared__ __align__(16) float    s_aT[KNNK*NHEAD];  // 2KB attn f32 [kk][h]
  __shared__ __align__(16) float    s_qv[DIM];
  __shared__ __align__(16) unsigned s_qp[128];
  __shared__ int   s_nidx[KNNK];
  __shared__ float s_ndist[KNNK];
  __shared__ float s_sb[NHEAD];

  u16*      s_w3gb = (u16*)s_d;           // f16 [8][128]
  unsigned* s_w3g32= (unsigned*)s_d;      // u32 [8][64]
  float*    s_sc   = s_d + 512;           // f32 [8][64]
  unsigned* s_ah2p = (unsigned*)s_d;      // u32 [64][8]  (after P6)

  const int bp = blockIdx.x;
  const int b  = bp >> 11;
  const int t  = threadIdx.x;
  const float* featB = features + (size_t)b * NPOINTS * DIM;
  const float* qrow  = qctx + (size_t)bp * DIM;

  // ---- P0 ----
  if (t < KNNK) {
    s_nidx[t]  = knn_idx[(size_t)bp*KNNK + t];
    s_ndist[t] = __half2float(knn_dist[(size_t)bp*KNNK + t]);
  }
  s_qv[t] = qrow[t];
  if (t < 128) s_qp[t] = pkh2(qrow[2*t], qrow[2*t+1]);
  __syncthreads();

  // ================= phase 1 =================
  // g-fold: g[c][h] = sum_{d in h} wk[c][d] q[d]  (padded f16-pair layout)
  {
    const unsigned* wk2 = (const unsigned*)wkT2;
    const int subg = t >> 6;
    const int c2l  = (t >> 1) & 31;
    u16* gps = (u16*)s_gp;
    #pragma unroll
    for (int h = 0; h < NHEAD; ++h) {
      float a = 0.f;
      #pragma unroll
      for (int dg = 0; dg < 16; ++dg) {
        const int d2 = h*16 + dg;
        a = fdot2f(wk2[d2*256 + t], s_qp[d2], a);
      }
      gps[(((h*4 + subg)*36 + c2l)<<1) + (t & 1)] = f2h(a);
    }
  }
  // w3g via w3k: w3g[h][j] = sum_{d in h} w3k[j][d] q[d]
  {
    const int h = t >> 5, jj = t & 31;
    uint4 q0 = *(const uint4*)(s_qp + h*16);
    uint4 q1 = *(const uint4*)(s_qp + h*16 + 4);
    uint4 q2 = *(const uint4*)(s_qp + h*16 + 8);
    uint4 q3 = *(const uint4*)(s_qp + h*16 + 12);
    const unsigned* w3k32 = (const unsigned*)w3kp;
    #pragma unroll
    for (int r = 0; r < 4; ++r) {
      const int j = jj*4 + r;
      const uint4* wr = (const uint4*)(w3k32 + ((h*D2 + j)<<4));
      uint4 w0 = wr[0], w1 = wr[1], w2 = wr[2], w3 = wr[3];
      float a = 0.f;
      a = fdot2f(w0.x,q0.x,a); a = fdot2f(w0.y,q0.y,a);
      a = fdot2f(w0.z,q0.z,a); a = fdot2f(w0.w,q0.w,a);
      a = fdot2f(w1.x,q1.x,a); a = fdot2f(w1.y,q1.y,a);
      a = fdot2f(w1.z,q1.z,a); a = fdot2f(w1.w,q1.w,a);
      a = fdot2f(w2.x,q2.x,a); a = fdot2f(w2.y,q2.y,a);
      a = fdot2f(w2.z,q2.z,a); a = fdot2f(w2.w,q2.w,a);
      a = fdot2f(w3.x,q3.x,a); a = fdot2f(w3.y,q3.y,a);
      a = fdot2f(w3.z,q3.z,a); a = fdot2f(w3.w,q3.w,a);
      s_w3gb[h*D2 + j] = f2h(a);
    }
  }
  // sb[h] = sum_{d in h} q[d] * (bk[d] + b3wk[d])
  if (t < NHEAD) {
    float s = 0.f;
    for (int d = 0; d < HDIM; ++d)
      s = fmaf(bkb3k[t*HDIM + d], s_qv[t*HDIM + d], s);
    s_sb[t] = s;
  }
  // h2[64][128] = relu(h1 @ w2 + b2) via v_mfma_f32_16x16x32_f16
  {
    const int w = t >> 6, l = t & 63;
    const int lm = l & 15, lg = l >> 4;
    const float dd = s_ndist[w*16 + lm];
    f16x8 af[2];
    #pragma unroll
    for (int ks = 0; ks < 2; ++ks) {
      const int i0 = ks*32 + lg*8;
      float4 w1a = *(const float4*)&de_w1[i0];
      float4 w1b = *(const float4*)&de_w1[i0+4];
      float4 b1a = *(const float4*)&de_b1[i0];
      float4 b1b = *(const float4*)&de_b1[i0+4];
      af[ks][0] = (_Float16)fmaxf(fmaf(dd, w1a.x, b1a.x), 0.f);
      af[ks][1] = (_Float16)fmaxf(fmaf(dd, w1a.y, b1a.y), 0.f);
      af[ks][2] = (_Float16)fmaxf(fmaf(dd, w1a.z, b1a.z), 0.f);
      af[ks][3] = (_Float16)fmaxf(fmaf(dd, w1a.w, b1a.w), 0.f);
      af[ks][4] = (_Float16)fmaxf(fmaf(dd, w1b.x, b1b.x), 0.f);
      af[ks][5] = (_Float16)fmaxf(fmaf(dd, w1b.y, b1b.y), 0.f);
      af[ks][6] = (_Float16)fmaxf(fmaf(dd, w1b.z, b1b.z), 0.f);
      af[ks][7] = (_Float16)fmaxf(fmaf(dd, w1b.w, b1b.w), 0.f);
    }
    f32x4 cacc[8];
    #pragma unroll
    for (int n = 0; n < 8; ++n) {
      float b2j = de_b2[n*16 + lm];
      f32x4 c = {b2j, b2j, b2j, b2j};
      f16x8 bf0, bf1;
      uint4 r0 = *(const uint4*)(w2frag + (((n*2+0)*64 + l)<<3));
      uint4 r1 = *(const uint4*)(w2frag + (((n*2+1)*64 + l)<<3));
      __builtin_memcpy(&bf0, &r0, 16);
      __builtin_memcpy(&bf1, &r1, 16);
      c = __builtin_amdgcn_mfma_f32_16x16x32_f16(af[0], bf0, c, 0, 0, 0);
      c = __builtin_amdgcn_mfma_f32_16x16x32_f16(af[1], bf1, c, 0, 0, 0);
      cacc[n] = c;
    }
    u16* h2w = (u16*)s_h2_32;
    #pragma unroll
    for (int n = 0; n < 8; ++n) {
      const int j = n*16 + lm;
      #pragma unroll
      for (int r = 0; r < 4; ++r) {
        const int kk = w*16 + lg*4 + r;
        h2w[kk*128 + (((j>>3)^(kk&15))<<3) + (j&7)] = f2h(fmaxf(cacc[n][r], 0.f));
      }
    }
  }
  __syncthreads();

  // ================= P5': scores =================
  // thread (kk = t>>2, sub = t&3): F slice [sub*64, +64) of row nidx[kk]
  {
    const int kk = t >> 2, sub = t & 3;
    const int kb = kk & 15;
    const float* Fr = featB + (size_t)s_nidx[kk]*DIM + sub*64;
    float part[8];
    #pragma unroll
    for (int h = 0; h < 8; ++h) part[h] = 0.f;
    #pragma unroll
    for (int half = 0; half < 2; ++half) {
      float4 f4[8];
      #pragma unroll
      for (int i = 0; i < 8; ++i) f4[i] = *(const float4*)&Fr[half*32 + i*4];
      unsigned fp[16];
      #pragma unroll
      for (int i = 0; i < 8; ++i) {
        fp[2*i]   = pkh2(f4[i].x, f4[i].y);
        fp[2*i+1] = pkh2(f4[i].z, f4[i].w);
      }
      #pragma unroll
      for (int h = 0; h < 8; ++h) {
        const unsigned* gp = s_gp + (h*4 + sub)*36 + half*16;
        uint4 g0 = *(const uint4*)(gp);
        uint4 g1 = *(const uint4*)(gp + 4);
        uint4 g2 = *(const uint4*)(gp + 8);
        uint4 g3 = *(const uint4*)(gp + 12);
        float a = part[h];
        a = fdot2f(fp[0], g0.x, a); a = fdot2f(fp[1], g0.y, a);
        a = fdot2f(fp[2], g0.z, a); a = fdot2f(fp[3], g0.w, a);
        a = fdot2f(fp[4], g1.x, a); a = fdot2f(fp[5], g1.y, a);
        a = fdot2f(fp[6], g1.z, a); a = fdot2f(fp[7], g1.w, a);
        a = fdot2f(fp[8], g2.x, a); a = fdot2f(fp[9], g2.y, a);
        a = fdot2f(fp[10],g2.z, a); a = fdot2f(fp[11],g2.w, a);
        a = fdot2f(fp[12],g3.x, a); a = fdot2f(fp[13],g3.y, a);
        a = fdot2f(fp[14],g3.z, a); a = fdot2f(fp[15],g3.w, a);
        part[h] = a;
      }
    }
    // h2 . w3g over j slice [sub*32, +32)
    uint4 h2v[4];
    #pragma unroll
    for (int i = 0; i < 4; ++i)
      h2v[i] = *(const uint4*)(s_h2_32 + kk*64 + ((((sub<<2)+i) ^ kb) << 2));
    #pragma unroll
    for (int h = 0; h < 8; ++h) {
      const uint4* wg = (const uint4*)(s_w3g32 + h*64 + sub*16);
      float a = part[h];
      #pragma unroll
      for (int i = 0; i < 4; ++i) {
        uint4 w = wg[i];
        a = fdot2f(h2v[i].x, w.x, a); a = fdot2f(h2v[i].y, w.y, a);
        a = fdot2f(h2v[i].z, w.z, a); a = fdot2f(h2v[i].w, w.w, a);
      }
      part[h] = a;
    }
    #pragma unroll
    for (int h = 0; h < 8; ++h) {
      part[h] += __shfl_xor(part[h], 1);
      part[h] += __shfl_xor(part[h], 2);
    }
    const int h0 = sub*2;
    s_sc[h0*64 + kk]     = (part[h0]   + s_sb[h0])   * SCALE_F;
    s_sc[(h0+1)*64 + kk] = (part[h0+1] + s_sb[h0+1]) * SCALE_F;
  }
  __syncthreads();

  // ================= P6: softmax =================
  {
    const int h = t >> 5, k2 = t & 31;
    float v0 = s_sc[h*64 + k2], v1 = s_sc[h*64 + k2 + 32];
    float mx = fmaxf(v0, v1);
    #pragma unroll
    for (int off = 16; off > 0; off >>= 1) mx = fmaxf(mx, __shfl_xor(mx, off, 32));
    float e0 = expf(v0 - mx), e1 = expf(v1 - mx);
    float sm = e0 + e1;
    #pragma unroll
    for (int off = 16; off > 0; off >>= 1) sm += __shfl_xor(sm, off, 32);
    float inv = 1.f / sm;
    s_aT[k2*NHEAD + h]      = e0 * inv;
    s_aT[(k2+32)*NHEAD + h] = e1 * inv;
  }
  __syncthreads();

  // ================= P8a: ah2 = attn @ h2 ; mF = attn @ F =================
  {
    const int jj2 = t & 63, hp = t >> 6;
    const int j = jj2*2;
    float a00=0.f, a01=0.f, a10=0.f, a11=0.f;
    #pragma unroll 4
    for (int kk = 0; kk < KNNK; ++kk) {
      unsigned hpw = s_h2_32[kk*64 + (((j>>3)^(kk&15))<<2) + ((j&7)>>1)];
      float2 hv = uph2(hpw);
      float2 av = *(const float2*)&s_aT[kk*NHEAD + hp*2];
      a00 = fmaf(av.x, hv.x, a00); a01 = fmaf(av.x, hv.y, a01);
      a10 = fmaf(av.y, hv.x, a10); a11 = fmaf(av.y, hv.y, a11);
    }
    s_ah2p[jj2*8 + hp*2]     = pkh2(a00, a01);
    s_ah2p[jj2*8 + hp*2 + 1] = pkh2(a10, a11);
  }
  // mF[h][c] = sum_kk attn[h,kk] * F[nidx[kk]][c]  (coalesced, prefetched)
  {
    const int h = t >> 5, c8 = t & 31;
    float mac[8];
    #pragma unroll
    for (int i = 0; i < 8; ++i) mac[i] = 0.f;
    const float* F0 = featB + (size_t)s_nidx[0]*DIM + c8*8;
    float4 fa = *(const float4*)F0, fb = *(const float4*)(F0+4);
    #pragma unroll 2
    for (int kk = 0; kk < KNNK; ++kk) {
      float4 ca = fa, cbv = fb;
      if (kk < KNNK-1) {
        const float* Fn = featB + (size_t)s_nidx[kk+1]*DIM + c8*8;
        fa = *(const float4*)Fn; fb = *(const float4*)(Fn+4);
      }
      float a = s_aT[kk*NHEAD + h];
      mac[0] = fmaf(a, ca.x, mac[0]); mac[1] = fmaf(a, ca.y, mac[1]);
      mac[2] = fmaf(a, ca.z, mac[2]); mac[3] = fmaf(a, ca.w, mac[3]);
      mac[4] = fmaf(a, cbv.x, mac[4]); mac[5] = fmaf(a, cbv.y, mac[5]);
      mac[6] = fmaf(a, cbv.z, mac[6]); mac[7] = fmaf(a, cbv.w, mac[7]);
    }
    *(float4*)&s_m[h*256 + c8*8]     = make_float4(mac[0], mac[1], mac[2], mac[3]);
    *(float4*)&s_m[h*256 + c8*8 + 4] = make_float4(mac[4], mac[5], mac[6], mac[7]);
  }
  __syncthreads();

  // ================= P9': ctx = mF.wv + ah2.w3v + cb =================
  {
    const int h = t >> 5;
    const float* mr = s_m + h*256;
    const unsigned* wv32 = (const unsigned*)wvB2;
    float acc = cbias[t];
    #pragma unroll 4
    for (int c4 = 0; c4 < 64; ++c4) {
      float4 m4 = *(const float4*)(mr + c4*4);
      float2 wa = uph2(wv32[(c4*2)*256 + t]);
      float2 wb = uph2(wv32[(c4*2+1)*256 + t]);
      acc = fmaf(wa.x, m4.x, acc); acc = fmaf(wa.y, m4.y, acc);
      acc = fmaf(wb.x, m4.z, acc); acc = fmaf(wb.y, m4.w, acc);
    }
    const unsigned* w3v32 = (const unsigned*)w3vp;
    #pragma unroll 4
    for (int j2 = 0; j2 < 64; ++j2)
      acc = fdot2f(s_ah2p[j2*8 + h], w3v32[j2*256 + t], acc);
    qctx[(size_t)bp*DIM + t] = acc;
  }
}

// ---------------------------------------------------------------------------
// Kernel 5: batched tail, 16 rows/block (unchanged).
// ---------------------------------------------------------------------------
__global__ __launch_bounds__(256) void se_kernel(
    const float* __restrict__ features,
    const float* __restrict__ wo,    const float* __restrict__ bo,
    const float* __restrict__ se_w1, const float* __restrict__ se_b1,
    const float* __restrict__ ln_g,  const float* __restrict__ ln_b,
    const float* __restrict__ se_w2, const float* __restrict__ se_b2,
    float* io)
{
  __shared__ __align__(16) float sA[16][DIM];
  __shared__ __align__(16) float sB[16][DIM];
  __shared__ __align__(16) float sAtt[16][DIM];
  __shared__ float s_mu[16], s_rs[16];
  const int r0 = blockIdx.x * 16, t = threadIdx.x;

  for (int r = 0; r < 16; ++r) {
    sA[r][t] = io[(size_t)(r0+r)*DIM + t];
    sB[r][t] = features[(size_t)(r0+r)*DIM + t];
  }
  __syncthreads();

  {
    float acc[16];
    const float bov = bo[t];
    #pragma unroll
    for (int r = 0; r < 16; ++r) acc[r] = bov;
    for (int d = 0; d < DIM; d += 4) {
      float w0 = wo[(d+0)*DIM+t], w1 = wo[(d+1)*DIM+t];
      float w2 = wo[(d+2)*DIM+t], w3v = wo[(d+3)*DIM+t];
      #pragma unroll
      for (int r = 0; r < 16; ++r) {
        float4 f4 = *(const float4*)&sA[r][d];
        acc[r] = fmaf(f4.x, w0, acc[r]); acc[r] = fmaf(f4.y, w1, acc[r]);
        acc[r] = fmaf(f4.z, w2, acc[r]); acc[r] = fmaf(f4.w, w3v, acc[r]);
      }
    }
    #pragma unroll
    for (int r = 0; r < 16; ++r) sAtt[r][t] = acc[r];
  }
  __syncthreads();

  {
    float acc[16];
    const float b1v = se_b1[t];
    #pragma unroll
    for (int r = 0; r < 16; ++r) acc[r] = b1v;
    for (int d = 0; d < DIM; d += 4) {
      float w0 = se_w1[(d+0)*DIM+t], w1 = se_w1[(d+1)*DIM+t];
      float w2 = se_w1[(d+2)*DIM+t], w3v = se_w1[(d+3)*DIM+t];
      #pragma unroll
      for (int r = 0; r < 16; ++r) {
        float4 f4 = *(const float4*)&sB[r][d];
        acc[r] = fmaf(f4.x, w0, acc[r]); acc[r] = fmaf(f4.y, w1, acc[r]);
        acc[r] = fmaf(f4.z, w2, acc[r]); acc[r] = fmaf(f4.w, w3v, acc[r]);
      }
    }
    for (int d = 0; d < DIM; d += 4) {
      float w0 = se_w1[(DIM+d+0)*DIM+t], w1 = se_w1[(DIM+d+1)*DIM+t];
      float w2 = se_w1[(DIM+d+2)*DIM+t], w3v = se_w1[(DIM+d+3)*DIM+t];
      #pragma unroll
      for (int r = 0; r < 16; ++r) {
        float4 f4 = *(const float4*)&sAtt[r][d];
        acc[r] = fmaf(f4.x, w0, acc[r]); acc[r] = fmaf(f4.y, w1, acc[r]);
        acc[r] = fmaf(f4.z, w2, acc[r]); acc[r] = fmaf(f4.w, w3v, acc[r]);
      }
    }
    __syncthreads();
    #pragma unroll
    for (int r = 0; r < 16; ++r) sA[r][t] = acc[r];
  }
  __syncthreads();

  {
    const int w = t >> 6, lane = t & 63;
    for (int i = 0; i < 4; ++i) {
      const int r = w*4 + i;
      float v0 = sA[r][lane], v1 = sA[r][lane+64];
      float v2 = sA[r][lane+128], v3 = sA[r][lane+192];
      float s1 = v0+v1+v2+v3;
      float s2 = v0*v0 + v1*v1 + v2*v2 + v3*v3;
      #pragma unroll
      for (int off = 32; off > 0; off >>= 1) {
        s1 += __shfl_xor(s1, off);
        s2 += __shfl_xor(s2, off);
      }
      if (lane == 0) {
        float mu = s1 * (1.f/256.f);
        s_mu[r] = mu;
        s_rs[r] = 1.f / sqrtf(s2 * (1.f/256.f) - mu*mu + 1e-5f);
      }
    }
  }
  __syncthreads();

  {
    const float lg = ln_g[t], lb = ln_b[t];
    #pragma unroll
    for (int r = 0; r < 16; ++r)
      sB[r][t] = fmaxf(fmaf((sA[r][t] - s_mu[r]) * s_rs[r], lg, lb), 0.f);
  }
  __syncthreads();

  {
    float acc[16];
    const float b2v = se_b2[t];
    #pragma unroll
    for (int r = 0; r < 16; ++r) acc[r] = b2v;
    for (int d = 0; d < DIM; d += 4) {
      float w0 = se_w2[(d+0)*DIM+t], w1 = se_w2[(d+1)*DIM+t];
      float w2 = se_w2[(d+2)*DIM+t], w3v = se_w2[(d+3)*DIM+t];
      #pragma unroll
      for (int r = 0; r < 16; ++r) {
        float4 f4 = *(const float4*)&sB[r][d];
        acc[r] = fmaf(f4.x, w0, acc[r]); acc[r] = fmaf(f4.y, w1, acc[r]);
        acc[r] = fmaf(f4.z, w2, acc[r]); acc[r] = fmaf(f4.w, w3v, acc[r]);
      }
    }
    #pragma unroll
    for (int r = 0; r < 16; ++r) io[(size_t)(r0+r)*DIM + t] = acc[r];
  }
}

extern "C" void kernel_launch(void* const* d_in, const int* in_sizes, int n_in,
                              void* d_out, int out_size, void* d_ws, size_t ws_size,
                              hipStream_t stream) {
  const float* features = (const float*)d_in[0];
  const float* xyz      = (const float*)d_in[1];
  const float* de_w1 = (const float*)d_in[2];
  const float* de_b1 = (const float*)d_in[3];
  const float* de_w2 = (const float*)d_in[4];
  const float* de_b2 = (const float*)d_in[5];
  const float* de_w3 = (const float*)d_in[6];
  const float* de_b3 = (const float*)d_in[7];
  const float* wq = (const float*)d_in[8];
  const float* bq = (const float*)d_in[9];
  const float* wk = (const float*)d_in[10];
  const float* bk = (const float*)d_in[11];
  const float* wv = (const float*)d_in[12];
  const float* bv = (const float*)d_in[13];
  const float* wo = (const float*)d_in[14];
  const float* bo = (const float*)d_in[15];
  const float* se_w1 = (const float*)d_in[16];
  const float* se_b1 = (const float*)d_in[17];
  const float* ln_g  = (const float*)d_in[18];
  const float* ln_b  = (const float*)d_in[19];
  const float* se_w2 = (const float*)d_in[20];
  const float* se_b2 = (const float*)d_in[21];

  // ws layout (< 2 MB):
  //   [0, 1MB)        knn_idx  int[4096][64]
  //   [+512KB)        knn_dist f16[4096][64]
  //   [+128KB)        wkT2   f16 pairs
  //   [+128KB)        wvB2   f16 pairs
  //   [+16KB)         w2frag f16 MFMA fragments
  //   [+64KB)         w3kp   f16 [8][128][32]
  //   [+64KB)         w3vp   f16 [64][256][2]
  //   [+1KB)          bkb3k  f32[256]
  //   [+1KB)          cb     f32[256]
  char* wsb = (char*)d_ws;
  int*    knn_idx  = (int*)wsb;
  __half* knn_dist = (__half*)(wsb + 1048576u);
  u16*   wkT2   = (u16*)(wsb + 1572864u);
  u16*   wvB2   = (u16*)(wsb + 1703936u);
  u16*   w2frag = (u16*)(wsb + 1835008u);
  u16*   w3kp   = (u16*)(wsb + 1851392u);
  u16*   w3vp   = (u16*)(wsb + 1916928u);
  float* bkb3k  = (float*)(wsb + 1982464u);
  float* cbias  = (float*)(wsb + 1983488u);

  knn_kernel<<<NROWS, 256, 0, stream>>>(xyz, knn_idx, knn_dist);
  prep_kernel<<<544, 256, 0, stream>>>(wk, wv, de_w2, wkT2, wvB2, w2frag);
  prep2_kernel<<<129, 256, 0, stream>>>(de_w3, de_b3, wk, wv, bk, bv,
                                        w3kp, w3vp, bkb3k, cbias);
  qproj_kernel<<<NROWS/16, 256, 0, stream>>>(features, wq, bq, (float*)d_out);
  fused_kernel<<<NROWS, 256, 0, stream>>>(
      features, (float*)d_out, knn_idx, knn_dist,
      wkT2, wvB2, w2frag, w3kp, w3vp,
      de_w1, de_b1, de_b2, bkb3k, cbias);
  se_kernel<<<NROWS/16, 256, 0, stream>>>(
      features, wo, bo, se_w1, se_b1, ln_g, ln_b, se_w2, se_b2, (float*)d_out);
}

// Round 5
// 329.773 us; speedup vs baseline: 1.4935x; 1.0810x over previous
//
#include <hip/hip_runtime.h>
#include <hip/hip_bf16.h>
#include <hip/hip_fp16.h>

#define NPOINTS 2048
#define BATCH   2
#define DIM     256
#define D2      128
#define D4      64
#define NHEAD   8
#define HDIM    32
#define KNNK    64
#define NROWS   (BATCH*NPOINTS)
#define SCALE_F 0.17677669529663687f

typedef unsigned short u16;
typedef _Float16 f16x8 __attribute__((ext_vector_type(8)));
typedef float f32x4 __attribute__((ext_vector_type(4)));

__device__ __forceinline__ u16 f2h(float f) {
  __half h = __float2half(f); u16 r; __builtin_memcpy(&r, &h, 2); return r;
}
__device__ __forceinline__ unsigned pkh2(float a, float b) {
  __half2 h = __floats2half2_rn(a, b); unsigned r; __builtin_memcpy(&r, &h, 4); return r;
}
__device__ __forceinline__ float2 uph2(unsigned u) {
  __half2 h; __builtin_memcpy(&h, &u, 4); return __half22float2(h);
}

#if __has_builtin(__builtin_amdgcn_fdot2)
typedef _Float16 hv2_t __attribute__((ext_vector_type(2)));
__device__ __forceinline__ float fdot2f(unsigned a, unsigned b, float c) {
  hv2_t x, y; __builtin_memcpy(&x, &a, 4); __builtin_memcpy(&y, &b, 4);
  return __builtin_amdgcn_fdot2(x, y, c, false);
}
#else
__device__ __forceinline__ float fdot2f(unsigned a, unsigned b, float c) {
  float2 x = uph2(a), y = uph2(b);
  return fmaf(x.x, y.x, fmaf(x.y, y.y, c));
}
#endif

// ---------------------------------------------------------------------------
// Kernel 1: exact KNN (64 smallest of 2048) per point. Distances stored f16.
// ---------------------------------------------------------------------------
__global__ __launch_bounds__(256) void knn_kernel(
    const float* __restrict__ xyz,
    int*    __restrict__ knn_idx,
    __half* __restrict__ knn_dist)
{
  __shared__ float dist[NPOINTS];
  __shared__ unsigned hist[256];
  __shared__ unsigned sh_sel, sh_below;

  const int bp = blockIdx.x;
  const int b  = bp >> 11;
  const int n  = bp & (NPOINTS - 1);
  const int t  = threadIdx.x;
  const float* P = xyz + (size_t)b * NPOINTS * 3;

  const float qx = P[n*3+0], qy = P[n*3+1], qz = P[n*3+2];
  const float r2n = qx*qx + qy*qy + qz*qz;
  for (int m = t; m < NPOINTS; m += 256) {
    float x = P[m*3+0], y = P[m*3+1], z = P[m*3+2];
    float r2m = x*x + y*y + z*z;
    float dt  = x*qx + y*qy + z*qz;
    float sq  = r2n + r2m - 2.f*dt;
    sq = fmaxf(sq, 0.f);
    dist[m] = (sq > 0.f) ? sqrtf(sq) : 0.f;
  }
  __syncthreads();

  unsigned prefix = 0u;
  int k_need = KNNK;
  for (int pass = 0; pass < 4; ++pass) {
    const int shift = 24 - pass*8;
    hist[t] = 0u;
    __syncthreads();
    for (int m = t; m < NPOINTS; m += 256) {
      unsigned bits = __float_as_uint(dist[m]);
      if (((bits >> shift) >> 8) == prefix)
        atomicAdd(&hist[(bits >> shift) & 255u], 1u);
    }
    __syncthreads();
    if (t < 64) {
      unsigned s0 = hist[t*4+0], s1 = hist[t*4+1], s2 = hist[t*4+2], s3 = hist[t*4+3];
      unsigned lsum = s0 + s1 + s2 + s3;
      unsigned scan = lsum;
      #pragma unroll
      for (int off = 1; off < 64; off <<= 1) {
        unsigned o = __shfl_up(scan, off);
        if (t >= off) scan += o;
      }
      unsigned excl = scan - lsum;
      unsigned kk = (unsigned)k_need;
      if (excl < kk && kk <= excl + lsum) {
        unsigned below = excl; int bin = t*4;
        if (kk > below + s0) { below += s0; bin++;
          if (kk > below + s1) { below += s1; bin++;
            if (kk > below + s2) { below += s2; bin++; } } }
        sh_sel = (unsigned)bin; sh_below = below;
      }
    }
    __syncthreads();
    prefix = (prefix << 8) | sh_sel;
    k_need -= (int)sh_below;
    __syncthreads();
  }
  const unsigned Tbits = prefix;
  const int base = KNNK - k_need;

  if (t < 64) {
    int*    oi = knn_idx  + (size_t)bp * KNNK;
    __half* od = knn_dist + (size_t)bp * KNNK;
    int taken = 0;
    for (int c = 0; c < NPOINTS/64; ++c) {
      int m = c*64 + t;
      float dv = dist[m];
      bool lt = (__float_as_uint(dv) < Tbits);
      unsigned long long msk = __ballot(lt);
      int off = __popcll(msk & ((1ull << t) - 1ull));
      if (lt) { oi[taken+off] = m; od[taken+off] = __float2half(dv); }
      taken += __popcll(msk);
    }
    int eq = 0;
    for (int c = 0; c < NPOINTS/64 && eq < k_need; ++c) {
      int m = c*64 + t;
      float dv = dist[m];
      bool e = (__float_as_uint(dv) == Tbits);
      unsigned long long msk = __ballot(e);
      int off = __popcll(msk & ((1ull << t) - 1ull));
      if (e && (eq + off) < k_need) { oi[base+eq+off] = m; od[base+eq+off] = __float2half(dv); }
      eq += __popcll(msk);
    }
  }
}

// ---------------------------------------------------------------------------
// Kernel 2: elementwise weight repack (f16) into ws.
// ---------------------------------------------------------------------------
__global__ __launch_bounds__(256) void prep_kernel(
    const float* __restrict__ wk, const float* __restrict__ wv,
    const float* __restrict__ de_w2,
    u16* __restrict__ wkT2, u16* __restrict__ wvB2, u16* __restrict__ w2frag)
{
  int tid = blockIdx.x*256 + threadIdx.x;
  if (tid < 65536) {
    int d = tid >> 8, c = tid & 255;
    wkT2[(d>>1)*512 + c*2 + (d&1)] = f2h(wk[c*DIM + d]);
  } else if (tid < 131072) {
    int o = tid - 65536; int c = o >> 8, d = o & 255;
    wvB2[(c>>1)*512 + d*2 + (c&1)] = f2h(wv[c*DIM + d]);
  } else if (tid < 139264) {
    int o = tid - 131072;            // 0..8191
    int e = o & 7, l = (o >> 3) & 63, ks = (o >> 9) & 1, n = o >> 10;
    int i = ks*32 + ((l >> 4) << 3) + e;
    int j = n*16 + (l & 15);
    w2frag[o] = f2h(de_w2[i*D2 + j]);
  }
}

// ---------------------------------------------------------------------------
// Kernel 2b: weight-fold GEMMs (w3k = de_w3@wk, w3v = de_w3@wv, bias folds).
// ---------------------------------------------------------------------------
__global__ __launch_bounds__(256) void prep2_kernel(
    const float* __restrict__ de_w3, const float* __restrict__ de_b3,
    const float* __restrict__ wk,    const float* __restrict__ wv,
    const float* __restrict__ bk,    const float* __restrict__ bv,
    u16* __restrict__ w3kp, u16* __restrict__ w3vp,
    float* __restrict__ bkb3k, float* __restrict__ cbias)
{
  const int j = blockIdx.x, t = threadIdx.x;
  float ak = 0.f, av = 0.f;
  if (j < D2) {
    const float* wrow = de_w3 + (size_t)j*DIM;
    #pragma unroll 4
    for (int c = 0; c < DIM; ++c) {
      float w = wrow[c];
      ak = fmaf(w, wk[c*DIM + t], ak);
      av = fmaf(w, wv[c*DIM + t], av);
    }
    w3kp[(((t>>5)*D2 + j)<<5) + (t&31)] = f2h(ak);
    w3vp[(j>>1)*512 + t*2 + (j&1)]      = f2h(av);
  } else {
    #pragma unroll 4
    for (int c = 0; c < DIM; ++c) {
      float w = de_b3[c];
      ak = fmaf(w, wk[c*DIM + t], ak);
      av = fmaf(w, wv[c*DIM + t], av);
    }
    bkb3k[t] = bk[t] + ak;
    cbias[t] = bv[t] + av;
  }
}

// ---------------------------------------------------------------------------
// Kernel 3: batched q projection, 16 rows/block. q -> d_out (scratch).
// ---------------------------------------------------------------------------
__global__ __launch_bounds__(256) void qproj_kernel(
    const float* __restrict__ features, const float* __restrict__ wq,
    const float* __restrict__ bq, float* __restrict__ qout)
{
  __shared__ __align__(16) float sf[16][DIM];
  const int r0 = blockIdx.x * 16, t = threadIdx.x;
  for (int r = 0; r < 16; ++r) sf[r][t] = features[(size_t)(r0+r)*DIM + t];
  __syncthreads();
  float acc[16];
  const float bqv = bq[t];
  #pragma unroll
  for (int r = 0; r < 16; ++r) acc[r] = bqv;
  for (int d = 0; d < DIM; d += 4) {
    float w0 = wq[(d+0)*DIM+t], w1 = wq[(d+1)*DIM+t];
    float w2 = wq[(d+2)*DIM+t], w3v = wq[(d+3)*DIM+t];
    #pragma unroll
    for (int r = 0; r < 16; ++r) {
      float4 f4 = *(const float4*)&sf[r][d];
      acc[r] = fmaf(f4.x, w0, acc[r]); acc[r] = fmaf(f4.y, w1, acc[r]);
      acc[r] = fmaf(f4.z, w2, acc[r]); acc[r] = fmaf(f4.w, w3v, acc[r]);
    }
  }
  #pragma unroll
  for (int r = 0; r < 16; ++r) qout[(size_t)(r0+r)*DIM + t] = acc[r];
}

// ---------------------------------------------------------------------------
// Kernel 4: fused per-point pipeline.
//   LDS pool 31.8KB (aliased regions) -> 5 blocks/CU.
//   h2-MFMA n-split per wave (w2frag read once per block).
//   P5' interleaved F chunks (64B-contiguous per quad per instruction).
//   mF c-split per wave (each F row read once per block).
// ---------------------------------------------------------------------------
__global__ __launch_bounds__(256, 5) void fused_kernel(
    const float* __restrict__ features,
    float* __restrict__ qctx,                       // d_out: q in, ctx out
    const int*    __restrict__ knn_idx,
    const __half* __restrict__ knn_dist,
    const u16* __restrict__ wkT2, const u16* __restrict__ wvB2,
    const u16* __restrict__ w2frag,
    const u16* __restrict__ w3kp, const u16* __restrict__ w3vp,
    const float* __restrict__ de_w1, const float* __restrict__ de_b1,
    const float* __restrict__ de_b2,
    const float* __restrict__ bkb3k, const float* __restrict__ cbias)
{
  // LDS pool with lifetime-based aliasing (31776 B total):
  //  [0,16K)      s_h2   h2 f16 pairs, swizzled        (phase1 -> P8a)
  //  [16K,24K)    s_gp   g f16 pairs [8][128]u32 (4KB, phase1 -> P5')
  //               s_m    mF f32 [8][256]         (8KB, P8a -> P9')
  //  [24K,28K)    s_d    w3gb f16[8][128] (2K) + sc f32[8][64] (2K)
  //               -> ah2p u32[64][8] (2K) after P6
  //  [28K,30K)    s_qv f32[256] (P0 -> phase1)  /  s_aT f32[64][8] (P6 -> P9')
  //  [30K, +512)  s_qp u32[128]
  //  then nidx[64], ndist[64], sb[8]
  __shared__ __align__(16) char smem[31776];
  unsigned* s_h2_32 = (unsigned*)(smem);
  unsigned* s_gp32  = (unsigned*)(smem + 16384);
  float*    s_m     = (float*)(smem + 16384);
  float*    s_d     = (float*)(smem + 24576);
  float*    s_qv    = (float*)(smem + 28672);
  float*    s_aT    = (float*)(smem + 28672);
  unsigned* s_qp    = (unsigned*)(smem + 30720);
  int*      s_nidx  = (int*)(smem + 31232);
  float*    s_ndist = (float*)(smem + 31488);
  float*    s_sb    = (float*)(smem + 31744);

  u16*      s_w3gb = (u16*)s_d;           // f16 [8][128]
  unsigned* s_w3g32= (unsigned*)s_d;      // u32 [8][64]
  float*    s_sc   = s_d + 512;           // f32 [8][64]
  unsigned* s_ah2p = (unsigned*)s_d;      // u32 [64][8]  (after P6)

  const int bp = blockIdx.x;
  const int b  = bp >> 11;
  const int t  = threadIdx.x;
  const float* featB = features + (size_t)b * NPOINTS * DIM;
  const float* qrow  = qctx + (size_t)bp * DIM;

  // ---- P0 ----
  if (t < KNNK) {
    s_nidx[t]  = knn_idx[(size_t)bp*KNNK + t];
    s_ndist[t] = __half2float(knn_dist[(size_t)bp*KNNK + t]);
  }
  s_qv[t] = qrow[t];
  if (t < 128) s_qp[t] = pkh2(qrow[2*t], qrow[2*t+1]);
  __syncthreads();

  // ================= phase 1 =================
  // g-fold: g[c][h] = sum_{d in h} wk[c][d] q[d]
  {
    const unsigned* wk2 = (const unsigned*)wkT2;
    u16* gps = (u16*)s_gp32;
    #pragma unroll
    for (int h = 0; h < NHEAD; ++h) {
      float a = 0.f;
      #pragma unroll
      for (int dg = 0; dg < 16; ++dg) {
        const int d2 = h*16 + dg;
        a = fdot2f(wk2[d2*256 + t], s_qp[d2], a);
      }
      gps[h*256 + t] = f2h(a);      // [h][c] f16, pairs over c
    }
  }
  // w3g via w3k: w3g[h][j] = sum_{d in h} w3k[j][d] q[d]
  {
    const int h = t >> 5, jj = t & 31;
    uint4 q0 = *(const uint4*)(s_qp + h*16);
    uint4 q1 = *(const uint4*)(s_qp + h*16 + 4);
    uint4 q2 = *(const uint4*)(s_qp + h*16 + 8);
    uint4 q3 = *(const uint4*)(s_qp + h*16 + 12);
    const unsigned* w3k32 = (const unsigned*)w3kp;
    #pragma unroll
    for (int r = 0; r < 4; ++r) {
      const int j = jj*4 + r;
      const uint4* wr = (const uint4*)(w3k32 + ((h*D2 + j)<<4));
      uint4 w0 = wr[0], w1 = wr[1], w2 = wr[2], w3 = wr[3];
      float a = 0.f;
      a = fdot2f(w0.x,q0.x,a); a = fdot2f(w0.y,q0.y,a);
      a = fdot2f(w0.z,q0.z,a); a = fdot2f(w0.w,q0.w,a);
      a = fdot2f(w1.x,q1.x,a); a = fdot2f(w1.y,q1.y,a);
      a = fdot2f(w1.z,q1.z,a); a = fdot2f(w1.w,q1.w,a);
      a = fdot2f(w2.x,q2.x,a); a = fdot2f(w2.y,q2.y,a);
      a = fdot2f(w2.z,q2.z,a); a = fdot2f(w2.w,q2.w,a);
      a = fdot2f(w3.x,q3.x,a); a = fdot2f(w3.y,q3.y,a);
      a = fdot2f(w3.z,q3.z,a); a = fdot2f(w3.w,q3.w,a);
      s_w3gb[h*D2 + j] = f2h(a);
    }
  }
  // sb[h] = sum_{d in h} q[d] * (bk[d] + b3wk[d])
  if (t < NHEAD) {
    float s = 0.f;
    for (int d = 0; d < HDIM; ++d)
      s = fmaf(bkb3k[t*HDIM + d], s_qv[t*HDIM + d], s);
    s_sb[t] = s;
  }
  // h2[64][128] = relu(h1 @ w2 + b2) via MFMA; wave w handles n in {2w,2w+1}
  // for ALL four 16-row kk-tiles (w2frag read once per block).
  {
    const int w = t >> 6, l = t & 63;
    const int lm = l & 15, lg = l >> 4;
    f16x8 af[4][2];
    #pragma unroll
    for (int ks = 0; ks < 2; ++ks) {
      const int i0 = ks*32 + lg*8;
      float4 w1a = *(const float4*)&de_w1[i0];
      float4 w1b = *(const float4*)&de_w1[i0+4];
      float4 b1a = *(const float4*)&de_b1[i0];
      float4 b1b = *(const float4*)&de_b1[i0+4];
      #pragma unroll
      for (int kt = 0; kt < 4; ++kt) {
        const float dd = s_ndist[kt*16 + lm];
        af[kt][ks][0] = (_Float16)fmaxf(fmaf(dd, w1a.x, b1a.x), 0.f);
        af[kt][ks][1] = (_Float16)fmaxf(fmaf(dd, w1a.y, b1a.y), 0.f);
        af[kt][ks][2] = (_Float16)fmaxf(fmaf(dd, w1a.z, b1a.z), 0.f);
        af[kt][ks][3] = (_Float16)fmaxf(fmaf(dd, w1a.w, b1a.w), 0.f);
        af[kt][ks][4] = (_Float16)fmaxf(fmaf(dd, w1b.x, b1b.x), 0.f);
        af[kt][ks][5] = (_Float16)fmaxf(fmaf(dd, w1b.y, b1b.y), 0.f);
        af[kt][ks][6] = (_Float16)fmaxf(fmaf(dd, w1b.z, b1b.z), 0.f);
        af[kt][ks][7] = (_Float16)fmaxf(fmaf(dd, w1b.w, b1b.w), 0.f);
      }
    }
    u16* h2w = (u16*)s_h2_32;
    #pragma unroll
    for (int ni = 0; ni < 2; ++ni) {
      const int n = 2*w + ni;
      const int j = n*16 + lm;
      f16x8 bf0, bf1;
      uint4 r0 = *(const uint4*)(w2frag + (((n*2+0)*64 + l)<<3));
      uint4 r1 = *(const uint4*)(w2frag + (((n*2+1)*64 + l)<<3));
      __builtin_memcpy(&bf0, &r0, 16);
      __builtin_memcpy(&bf1, &r1, 16);
      const float b2j = de_b2[j];
      #pragma unroll
      for (int kt = 0; kt < 4; ++kt) {
        f32x4 c = {b2j, b2j, b2j, b2j};
        c = __builtin_amdgcn_mfma_f32_16x16x32_f16(af[kt][0], bf0, c, 0, 0, 0);
        c = __builtin_amdgcn_mfma_f32_16x16x32_f16(af[kt][1], bf1, c, 0, 0, 0);
        #pragma unroll
        for (int r = 0; r < 4; ++r) {
          const int kk = kt*16 + lg*4 + r;
          h2w[kk*128 + (((j>>3)^(kk&15))<<3) + (j&7)] = f2h(fmaxf(c[r], 0.f));
        }
      }
    }
  }
  __syncthreads();

  // ================= P5': scores =================
  // thread (kk = t>>2, sub = t&3): interleaved 16B chunks (i*4+sub) so each
  // quad reads 64B contiguous per instruction.
  {
    const int kk = t >> 2, sub = t & 3;
    const int kb = kk & 15;
    const float* Fr = featB + (size_t)s_nidx[kk]*DIM;
    float part[8];
    #pragma unroll
    for (int h = 0; h < 8; ++h) part[h] = 0.f;
    #pragma unroll 4
    for (int i = 0; i < 16; ++i) {
      const int ch = i*4 + sub;                  // float4-chunk 0..63
      float4 f = *(const float4*)&Fr[ch*4];
      unsigned p0 = pkh2(f.x, f.y), p1 = pkh2(f.z, f.w);
      #pragma unroll
      for (int h = 0; h < 8; ++h) {
        uint2 g = *(const uint2*)(s_gp32 + h*128 + ch*2);
        part[h] = fdot2f(p1, g.y, fdot2f(p0, g.x, part[h]));
      }
    }
    // h2 . w3g over j slice [sub*32, +32)
    uint4 h2v[4];
    #pragma unroll
    for (int i = 0; i < 4; ++i)
      h2v[i] = *(const uint4*)(s_h2_32 + kk*64 + ((((sub<<2)+i) ^ kb) << 2));
    #pragma unroll
    for (int h = 0; h < 8; ++h) {
      const uint4* wg = (const uint4*)(s_w3g32 + h*64 + sub*16);
      float a = part[h];
      #pragma unroll
      for (int i = 0; i < 4; ++i) {
        uint4 w = wg[i];
        a = fdot2f(h2v[i].x, w.x, a); a = fdot2f(h2v[i].y, w.y, a);
        a = fdot2f(h2v[i].z, w.z, a); a = fdot2f(h2v[i].w, w.w, a);
      }
      part[h] = a;
    }
    #pragma unroll
    for (int h = 0; h < 8; ++h) {
      part[h] += __shfl_xor(part[h], 1);
      part[h] += __shfl_xor(part[h], 2);
    }
    const int h0 = sub*2;
    s_sc[h0*64 + kk]     = (part[h0]   + s_sb[h0])   * SCALE_F;
    s_sc[(h0+1)*64 + kk] = (part[h0+1] + s_sb[h0+1]) * SCALE_F;
  }
  __syncthreads();

  // ================= P6: softmax =================
  {
    const int h = t >> 5, k2 = t & 31;
    float v0 = s_sc[h*64 + k2], v1 = s_sc[h*64 + k2 + 32];
    float mx = fmaxf(v0, v1);
    #pragma unroll
    for (int off = 16; off > 0; off >>= 1) mx = fmaxf(mx, __shfl_xor(mx, off, 32));
    float e0 = expf(v0 - mx), e1 = expf(v1 - mx);
    float sm = e0 + e1;
    #pragma unroll
    for (int off = 16; off > 0; off >>= 1) sm += __shfl_xor(sm, off, 32);
    float inv = 1.f / sm;
    s_aT[k2*NHEAD + h]      = e0 * inv;
    s_aT[(k2+32)*NHEAD + h] = e1 * inv;
  }
  __syncthreads();

  // ================= P8a: ah2 = attn @ h2 ; mF = attn @ F =================
  {
    const int jj2 = t & 63, hp = t >> 6;
    const int j = jj2*2;
    float a00=0.f, a01=0.f, a10=0.f, a11=0.f;
    #pragma unroll 4
    for (int kk = 0; kk < KNNK; ++kk) {
      unsigned hpw = s_h2_32[kk*64 + (((j>>3)^(kk&15))<<2) + ((j&7)>>1)];
      float2 hv = uph2(hpw);
      float2 av = *(const float2*)&s_aT[kk*NHEAD + hp*2];
      a00 = fmaf(av.x, hv.x, a00); a01 = fmaf(av.x, hv.y, a01);
      a10 = fmaf(av.y, hv.x, a10); a11 = fmaf(av.y, hv.y, a11);
    }
    s_ah2p[jj2*8 + hp*2]     = pkh2(a00, a01);
    s_ah2p[jj2*8 + hp*2 + 1] = pkh2(a10, a11);
  }
  // mF c-split: wave w owns c in [64w, 64w+64); lane = (h = l>>3, c8 = l&7).
  // Head-lanes with equal c8 read the same 32B -> broadcast; each F row is
  // read exactly once per block.
  {
    const int w = t >> 6, l = t & 63;
    const int h = l >> 3, c8 = l & 7;
    const int coff = w*64 + c8*8;
    float mac[8];
    #pragma unroll
    for (int i = 0; i < 8; ++i) mac[i] = 0.f;
    const float* F0 = featB + (size_t)s_nidx[0]*DIM + coff;
    float4 fa = *(const float4*)F0, fb = *(const float4*)(F0+4);
    #pragma unroll 2
    for (int kk = 0; kk < KNNK; ++kk) {
      float4 ca = fa, cbv = fb;
      if (kk < KNNK-1) {
        const float* Fn = featB + (size_t)s_nidx[kk+1]*DIM + coff;
        fa = *(const float4*)Fn; fb = *(const float4*)(Fn+4);
      }
      float a = s_aT[kk*NHEAD + h];
      mac[0] = fmaf(a, ca.x, mac[0]); mac[1] = fmaf(a, ca.y, mac[1]);
      mac[2] = fmaf(a, ca.z, mac[2]); mac[3] = fmaf(a, ca.w, mac[3]);
      mac[4] = fmaf(a, cbv.x, mac[4]); mac[5] = fmaf(a, cbv.y, mac[5]);
      mac[6] = fmaf(a, cbv.z, mac[6]); mac[7] = fmaf(a, cbv.w, mac[7]);
    }
    *(float4*)&s_m[h*256 + coff]     = make_float4(mac[0], mac[1], mac[2], mac[3]);
    *(float4*)&s_m[h*256 + coff + 4] = make_float4(mac[4], mac[5], mac[6], mac[7]);
  }
  __syncthreads();

  // ================= P9': ctx = mF.wv + ah2.w3v + cb =================
  {
    const int h = t >> 5;
    const float* mr = s_m + h*256;
    const unsigned* wv32 = (const unsigned*)wvB2;
    float acc = cbias[t];
    #pragma unroll 4
    for (int c4 = 0; c4 < 64; ++c4) {
      float4 m4 = *(const float4*)(mr + c4*4);
      float2 wa = uph2(wv32[(c4*2)*256 + t]);
      float2 wb = uph2(wv32[(c4*2+1)*256 + t]);
      acc = fmaf(wa.x, m4.x, acc); acc = fmaf(wa.y, m4.y, acc);
      acc = fmaf(wb.x, m4.z, acc); acc = fmaf(wb.y, m4.w, acc);
    }
    const unsigned* w3v32 = (const unsigned*)w3vp;
    #pragma unroll 4
    for (int j2 = 0; j2 < 64; ++j2)
      acc = fdot2f(s_ah2p[j2*8 + h], w3v32[j2*256 + t], acc);
    qctx[(size_t)bp*DIM + t] = acc;
  }
}

// ---------------------------------------------------------------------------
// Kernel 5: batched tail, 16 rows/block (unchanged).
// ---------------------------------------------------------------------------
__global__ __launch_bounds__(256) void se_kernel(
    const float* __restrict__ features,
    const float* __restrict__ wo,    const float* __restrict__ bo,
    const float* __restrict__ se_w1, const float* __restrict__ se_b1,
    const float* __restrict__ ln_g,  const float* __restrict__ ln_b,
    const float* __restrict__ se_w2, const float* __restrict__ se_b2,
    float* io)
{
  __shared__ __align__(16) float sA[16][DIM];
  __shared__ __align__(16) float sB[16][DIM];
  __shared__ __align__(16) float sAtt[16][DIM];
  __shared__ float s_mu[16], s_rs[16];
  const int r0 = blockIdx.x * 16, t = threadIdx.x;

  for (int r = 0; r < 16; ++r) {
    sA[r][t] = io[(size_t)(r0+r)*DIM + t];
    sB[r][t] = features[(size_t)(r0+r)*DIM + t];
  }
  __syncthreads();

  {
    float acc[16];
    const float bov = bo[t];
    #pragma unroll
    for (int r = 0; r < 16; ++r) acc[r] = bov;
    for (int d = 0; d < DIM; d += 4) {
      float w0 = wo[(d+0)*DIM+t], w1 = wo[(d+1)*DIM+t];
      float w2 = wo[(d+2)*DIM+t], w3v = wo[(d+3)*DIM+t];
      #pragma unroll
      for (int r = 0; r < 16; ++r) {
        float4 f4 = *(const float4*)&sA[r][d];
        acc[r] = fmaf(f4.x, w0, acc[r]); acc[r] = fmaf(f4.y, w1, acc[r]);
        acc[r] = fmaf(f4.z, w2, acc[r]); acc[r] = fmaf(f4.w, w3v, acc[r]);
      }
    }
    #pragma unroll
    for (int r = 0; r < 16; ++r) sAtt[r][t] = acc[r];
  }
  __syncthreads();

  {
    float acc[16];
    const float b1v = se_b1[t];
    #pragma unroll
    for (int r = 0; r < 16; ++r) acc[r] = b1v;
    for (int d = 0; d < DIM; d += 4) {
      float w0 = se_w1[(d+0)*DIM+t], w1 = se_w1[(d+1)*DIM+t];
      float w2 = se_w1[(d+2)*DIM+t], w3v = se_w1[(d+3)*DIM+t];
      #pragma unroll
      for (int r = 0; r < 16; ++r) {
        float4 f4 = *(const float4*)&sB[r][d];
        acc[r] = fmaf(f4.x, w0, acc[r]); acc[r] = fmaf(f4.y, w1, acc[r]);
        acc[r] = fmaf(f4.z, w2, acc[r]); acc[r] = fmaf(f4.w, w3v, acc[r]);
      }
    }
    for (int d = 0; d < DIM; d += 4) {
      float w0 = se_w1[(DIM+d+0)*DIM+t], w1 = se_w1[(DIM+d+1)*DIM+t];
      float w2 = se_w1[(DIM+d+2)*DIM+t], w3v = se_w1[(DIM+d+3)*DIM+t];
      #pragma unroll
      for (int r = 0; r < 16; ++r) {
        float4 f4 = *(const float4*)&sAtt[r][d];
        acc[r] = fmaf(f4.x, w0, acc[r]); acc[r] = fmaf(f4.y, w1, acc[r]);
        acc[r] = fmaf(f4.z, w2, acc[r]); acc[r] = fmaf(f4.w, w3v, acc[r]);
      }
    }
    __syncthreads();
    #pragma unroll
    for (int r = 0; r < 16; ++r) sA[r][t] = acc[r];
  }
  __syncthreads();

  {
    const int w = t >> 6, lane = t & 63;
    for (int i = 0; i < 4; ++i) {
      const int r = w*4 + i;
      float v0 = sA[r][lane], v1 = sA[r][lane+64];
      float v2 = sA[r][lane+128], v3 = sA[r][lane+192];
      float s1 = v0+v1+v2+v3;
      float s2 = v0*v0 + v1*v1 + v2*v2 + v3*v3;
      #pragma unroll
      for (int off = 32; off > 0; off >>= 1) {
        s1 += __shfl_xor(s1, off);
        s2 += __shfl_xor(s2, off);
      }
      if (lane == 0) {
        float mu = s1 * (1.f/256.f);
        s_mu[r] = mu;
        s_rs[r] = 1.f / sqrtf(s2 * (1.f/256.f) - mu*mu + 1e-5f);
      }
    }
  }
  __syncthreads();

  {
    const float lg = ln_g[t], lb = ln_b[t];
    #pragma unroll
    for (int r = 0; r < 16; ++r)
      sB[r][t] = fmaxf(fmaf((sA[r][t] - s_mu[r]) * s_rs[r], lg, lb), 0.f);
  }
  __syncthreads();

  {
    float acc[16];
    const float b2v = se_b2[t];
    #pragma unroll
    for (int r = 0; r < 16; ++r) acc[r] = b2v;
    for (int d = 0; d < DIM; d += 4) {
      float w0 = se_w2[(d+0)*DIM+t], w1 = se_w2[(d+1)*DIM+t];
      float w2 = se_w2[(d+2)*DIM+t], w3v = se_w2[(d+3)*DIM+t];
      #pragma unroll
      for (int r = 0; r < 16; ++r) {
        float4 f4 = *(const float4*)&sB[r][d];
        acc[r] = fmaf(f4.x, w0, acc[r]); acc[r] = fmaf(f4.y, w1, acc[r]);
        acc[r] = fmaf(f4.z, w2, acc[r]); acc[r] = fmaf(f4.w, w3v, acc[r]);
      }
    }
    #pragma unroll
    for (int r = 0; r < 16; ++r) io[(size_t)(r0+r)*DIM + t] = acc[r];
  }
}

extern "C" void kernel_launch(void* const* d_in, const int* in_sizes, int n_in,
                              void* d_out, int out_size, void* d_ws, size_t ws_size,
                              hipStream_t stream) {
  const float* features = (const float*)d_in[0];
  const float* xyz      = (const float*)d_in[1];
  const float* de_w1 = (const float*)d_in[2];
  const float* de_b1 = (const float*)d_in[3];
  const float* de_w2 = (const float*)d_in[4];
  const float* de_b2 = (const float*)d_in[5];
  const float* de_w3 = (const float*)d_in[6];
  const float* de_b3 = (const float*)d_in[7];
  const float* wq = (const float*)d_in[8];
  const float* bq = (const float*)d_in[9];
  const float* wk = (const float*)d_in[10];
  const float* bk = (const float*)d_in[11];
  const float* wv = (const float*)d_in[12];
  const float* bv = (const float*)d_in[13];
  const float* wo = (const float*)d_in[14];
  const float* bo = (const float*)d_in[15];
  const float* se_w1 = (const float*)d_in[16];
  const float* se_b1 = (const float*)d_in[17];
  const float* ln_g  = (const float*)d_in[18];
  const float* ln_b  = (const float*)d_in[19];
  const float* se_w2 = (const float*)d_in[20];
  const float* se_b2 = (const float*)d_in[21];

  // ws layout (< 2 MB):
  char* wsb = (char*)d_ws;
  int*    knn_idx  = (int*)wsb;
  __half* knn_dist = (__half*)(wsb + 1048576u);
  u16*   wkT2   = (u16*)(wsb + 1572864u);
  u16*   wvB2   = (u16*)(wsb + 1703936u);
  u16*   w2frag = (u16*)(wsb + 1835008u);
  u16*   w3kp   = (u16*)(wsb + 1851392u);
  u16*   w3vp   = (u16*)(wsb + 1916928u);
  float* bkb3k  = (float*)(wsb + 1982464u);
  float* cbias  = (float*)(wsb + 1983488u);

  knn_kernel<<<NROWS, 256, 0, stream>>>(xyz, knn_idx, knn_dist);
  prep_kernel<<<544, 256, 0, stream>>>(wk, wv, de_w2, wkT2, wvB2, w2frag);
  prep2_kernel<<<129, 256, 0, stream>>>(de_w3, de_b3, wk, wv, bk, bv,
                                        w3kp, w3vp, bkb3k, cbias);
  qproj_kernel<<<NROWS/16, 256, 0, stream>>>(features, wq, bq, (float*)d_out);
  fused_kernel<<<NROWS, 256, 0, stream>>>(
      features, (float*)d_out, knn_idx, knn_dist,
      wkT2, wvB2, w2frag, w3kp, w3vp,
      de_w1, de_b1, de_b2, bkb3k, cbias);
  se_kernel<<<NROWS/16, 256, 0, stream>>>(
      features, wo, bo, se_w1, se_b1, ln_g, ln_b, se_w2, se_b2, (float*)d_out);
}